// Round 6
// baseline (560.458 us; speedup 1.0000x reference)
//
#include <hip/hip_runtime.h>

// out[N,256] = concat( x[N,128] @ Wx[128,128] + bx,
//                      segsum(edge_attr by src)[N,32] @ We[32,128] + be )
//
// Pipeline:
//   binA:   bucket packed (edge_id<<7 | node&127) by src>>7 (128-node buckets)
//   gather: per bucket, stream segment with 4-deep prefetch -> ds_add_f32 into
//           swizzled LDS agg -> coalesced bf16 flush
//   gemm:   MFMA bf16 16x16x32, weights in swizzled LDS, A-frags from global,
//           two half-passes to keep VGPR <= 128, no per-tile barriers.

#define BSHIFT    7
#define BSIZE     128
#define NBMAX     1024
#define SEG_CAP   3584    // pairs per bucket (mean ~2046, sigma ~45, +34 sigma)
#define CHUNK_A   8192
#define SPILL_CAP 65536

typedef short bf16x8 __attribute__((ext_vector_type(8)));
typedef float f32x4  __attribute__((ext_vector_type(4)));

__device__ __forceinline__ short f2bf(float f) {
    union { float f; unsigned u; } c; c.f = f;
    unsigned u = c.u;
    u += 0x7FFF + ((u >> 16) & 1);          // round-to-nearest-even
    return (short)(u >> 16);
}

// ---------- Pass A: bucket edges (packed 4B pairs) ----------
__global__ __launch_bounds__(256) void binA_kernel(
    const int* __restrict__ src, int E, int nb,
    unsigned* __restrict__ segs, int* __restrict__ gcnt,
    int2* __restrict__ spill, int* __restrict__ spillcnt)
{
    __shared__ unsigned pool[CHUNK_A];      // 32 KB
    __shared__ int hist[NBMAX];
    __shared__ int offs[NBMAX];
    __shared__ int lcur[NBMAX];
    __shared__ int gbase[NBMAX];
    __shared__ int gallow[NBMAX];
    __shared__ int wsum[4];

    int tid = threadIdx.x;
    int base = blockIdx.x * CHUNK_A;

    for (int i = tid; i < NBMAX; i += 256) hist[i] = 0;
    __syncthreads();

    for (int i = tid; i < CHUNK_A; i += 256) {
        int e = base + i;
        if (e < E) atomicAdd(&hist[src[e] >> BSHIFT], 1);
    }
    __syncthreads();

    // block exclusive scan: each thread owns buckets 4t..4t+3
    {
        int t4 = tid * 4;
        int c0 = hist[t4], c1 = hist[t4 + 1], c2 = hist[t4 + 2], c3 = hist[t4 + 3];
        int s = c0 + c1 + c2 + c3;
        int lane = tid & 63, wid = tid >> 6;
        int ws = s;
        #pragma unroll
        for (int d = 1; d < 64; d <<= 1) {
            int t = __shfl_up(ws, d);
            if (lane >= d) ws += t;
        }
        if (lane == 63) wsum[wid] = ws;
        __syncthreads();
        int woff = 0;
        #pragma unroll
        for (int w = 0; w < 4; ++w) if (w < wid) woff += wsum[w];
        int ex = woff + ws - s;
        offs[t4] = ex;               lcur[t4] = ex;
        offs[t4 + 1] = ex + c0;      lcur[t4 + 1] = ex + c0;
        offs[t4 + 2] = ex + c0 + c1; lcur[t4 + 2] = ex + c0 + c1;
        offs[t4 + 3] = ex + c0 + c1 + c2; lcur[t4 + 3] = ex + c0 + c1 + c2;
    }
    __syncthreads();

    // reserve global segment space
    {
        int t4 = tid * 4;
        #pragma unroll
        for (int u = 0; u < 4; ++u) {
            int b = t4 + u;
            if (b < nb) {
                int cnt = hist[b];
                int b0 = cnt ? atomicAdd(&gcnt[b], cnt) : 0;
                gbase[b] = b0;
                int allow = SEG_CAP - b0;
                if (allow < 0) allow = 0;
                if (allow > cnt) allow = cnt;
                gallow[b] = allow;
            }
        }
    }
    __syncthreads();

    // place packed pairs into LDS pool grouped by bucket
    for (int i = tid; i < CHUNK_A; i += 256) {
        int e = base + i;
        if (e < E) {
            int s = src[e];
            int b = s >> BSHIFT;
            int p = atomicAdd(&lcur[b], 1);
            pool[p] = ((unsigned)e << BSHIFT) | (unsigned)(s & (BSIZE - 1));
        }
    }
    __syncthreads();

    // coalesced flush
    int wid = tid >> 6, lane = tid & 63;
    for (int b = wid; b < nb; b += 4) {
        int cnt = hist[b];
        int off = offs[b];
        int allow = gallow[b];
        unsigned* dst = segs + (size_t)b * SEG_CAP + gbase[b];
        for (int i = lane; i < allow; i += 64)
            dst[i] = pool[off + i];
        int excess = cnt - allow;
        if (excess > 0) {                 // never in practice
            int sb;
            if (lane == 0) sb = atomicAdd(spillcnt, excess);
            sb = __shfl(sb, 0);
            for (int i = lane; i < excess; i += 64) {
                int sp = sb + i;
                if (sp < SPILL_CAP) {
                    unsigned pv = pool[off + allow + i];
                    spill[sp] = make_int2((int)(pv >> BSHIFT),
                                          (b << BSHIFT) | (int)(pv & (BSIZE - 1)));
                }
            }
        }
    }
}

// ---------- gather: LDS float-atomic accumulation, 4-deep prefetch ----------
__global__ __launch_bounds__(512) void gather_kernel(
    const unsigned* __restrict__ segs, const int* __restrict__ gcnt,
    const int2* __restrict__ spill, const int* __restrict__ spillcnt,
    const float4* __restrict__ ea4, unsigned short* __restrict__ aggbf, int N)
{
    __shared__ float sagg[BSIZE * 32];      // 16 KB, XOR-swizzled columns

    int tid = threadIdx.x;
    int b = blockIdx.x;
    int node0 = b << BSHIFT;

    for (int i = tid; i < BSIZE * 32; i += 512) sagg[i] = 0.f;
    __syncthreads();

    int segn = gcnt[b]; if (segn > SEG_CAP) segn = SEG_CAP;
    const unsigned* seg = segs + (size_t)b * SEG_CAP;

    int g = tid >> 3, q = tid & 7;          // 64 groups of 8 threads
    int cb = q * 4;

    int i = g;
    // 4-deep prefetch: 4 seg words + 4 edge rows in flight
    for (; i + 192 < segn; i += 256) {
        unsigned pe0 = seg[i];
        unsigned pe1 = seg[i + 64];
        unsigned pe2 = seg[i + 128];
        unsigned pe3 = seg[i + 192];
        float4 v0 = ea4[(size_t)(pe0 >> BSHIFT) * 8 + q];
        float4 v1 = ea4[(size_t)(pe1 >> BSHIFT) * 8 + q];
        float4 v2 = ea4[(size_t)(pe2 >> BSHIFT) * 8 + q];
        float4 v3 = ea4[(size_t)(pe3 >> BSHIFT) * 8 + q];
        int d0 = pe0 & (BSIZE - 1), sw0 = (d0 & 7) << 2;
        int d1 = pe1 & (BSIZE - 1), sw1 = (d1 & 7) << 2;
        int d2 = pe2 & (BSIZE - 1), sw2 = (d2 & 7) << 2;
        int d3 = pe3 & (BSIZE - 1), sw3 = (d3 & 7) << 2;
        atomicAdd(&sagg[d0 * 32 + ((cb + 0) ^ sw0)], v0.x);
        atomicAdd(&sagg[d0 * 32 + ((cb + 1) ^ sw0)], v0.y);
        atomicAdd(&sagg[d0 * 32 + ((cb + 2) ^ sw0)], v0.z);
        atomicAdd(&sagg[d0 * 32 + ((cb + 3) ^ sw0)], v0.w);
        atomicAdd(&sagg[d1 * 32 + ((cb + 0) ^ sw1)], v1.x);
        atomicAdd(&sagg[d1 * 32 + ((cb + 1) ^ sw1)], v1.y);
        atomicAdd(&sagg[d1 * 32 + ((cb + 2) ^ sw1)], v1.z);
        atomicAdd(&sagg[d1 * 32 + ((cb + 3) ^ sw1)], v1.w);
        atomicAdd(&sagg[d2 * 32 + ((cb + 0) ^ sw2)], v2.x);
        atomicAdd(&sagg[d2 * 32 + ((cb + 1) ^ sw2)], v2.y);
        atomicAdd(&sagg[d2 * 32 + ((cb + 2) ^ sw2)], v2.z);
        atomicAdd(&sagg[d2 * 32 + ((cb + 3) ^ sw2)], v2.w);
        atomicAdd(&sagg[d3 * 32 + ((cb + 0) ^ sw3)], v3.x);
        atomicAdd(&sagg[d3 * 32 + ((cb + 1) ^ sw3)], v3.y);
        atomicAdd(&sagg[d3 * 32 + ((cb + 2) ^ sw3)], v3.z);
        atomicAdd(&sagg[d3 * 32 + ((cb + 3) ^ sw3)], v3.w);
    }
    for (; i < segn; i += 64) {
        unsigned pe = seg[i];
        float4 v = ea4[(size_t)(pe >> BSHIFT) * 8 + q];
        int d = pe & (BSIZE - 1), sw = (d & 7) << 2;
        atomicAdd(&sagg[d * 32 + ((cb + 0) ^ sw)], v.x);
        atomicAdd(&sagg[d * 32 + ((cb + 1) ^ sw)], v.y);
        atomicAdd(&sagg[d * 32 + ((cb + 2) ^ sw)], v.z);
        atomicAdd(&sagg[d * 32 + ((cb + 3) ^ sw)], v.w);
    }

    // spill (never in practice)
    int nsp = *spillcnt; if (nsp > SPILL_CAP) nsp = SPILL_CAP;
    for (int k = tid; k < nsp; k += 512) {
        int2 p = spill[k];
        if ((p.y >> BSHIFT) == b) {
            int d = p.y & (BSIZE - 1), sw = (d & 7) << 2;
            for (int j = 0; j < 8; ++j) {
                float4 v = ea4[(size_t)p.x * 8 + j];
                atomicAdd(&sagg[d * 32 + ((j * 4 + 0) ^ sw)], v.x);
                atomicAdd(&sagg[d * 32 + ((j * 4 + 1) ^ sw)], v.y);
                atomicAdd(&sagg[d * 32 + ((j * 4 + 2) ^ sw)], v.z);
                atomicAdd(&sagg[d * 32 + ((j * 4 + 3) ^ sw)], v.w);
            }
        }
    }
    __syncthreads();

    // bf16 flush, coalesced
    for (int k = tid; k < BSIZE * 32; k += 512) {
        int d = k >> 5, c = k & 31;
        int node = node0 + d;
        if (node < N)
            aggbf[(size_t)node * 32 + c] = (unsigned short)f2bf(sagg[d * 32 + (c ^ ((d & 7) << 2))]);
    }
}

// ---------- fallback: atomic scatter + convert ----------
__global__ __launch_bounds__(256) void scatter_kernel(
    const float4* __restrict__ ea4, const int* __restrict__ src,
    float* __restrict__ agg, int nquads)
{
    int t = blockIdx.x * blockDim.x + threadIdx.x;
    if (t >= nquads) return;
    int e = t >> 3, q = t & 7;
    float4 v = ea4[t];
    int node = src[e];
    float* dst = agg + (size_t)node * 32 + q * 4;
    atomicAdd(dst + 0, v.x); atomicAdd(dst + 1, v.y);
    atomicAdd(dst + 2, v.z); atomicAdd(dst + 3, v.w);
}

__global__ __launch_bounds__(256) void cvt_kernel(
    const float* __restrict__ agg, unsigned short* __restrict__ aggbf, int n)
{
    int t = blockIdx.x * blockDim.x + threadIdx.x;
    if (t < n) aggbf[t] = (unsigned short)f2bf(agg[t]);
}

// ---------- MFMA bf16 fused dual-GEMM ----------
// 512 threads = 8 waves; wave w computes rows [t*128 + w*16, +16) x 256 cols.
// Wx^T, We^T staged once per block in swizzled LDS; x/agg A-frags from global.
// Two half-passes over output columns keep live acc at 8 f32x4 (32 VGPR).
__global__ __launch_bounds__(512, 4) void mfma_gemm(
    const float* __restrict__ x, const unsigned short* __restrict__ aggbf,
    const float* __restrict__ Wx, const float* __restrict__ bx,
    const float* __restrict__ We, const float* __restrict__ be,
    float* __restrict__ out, int N, int ntiles)
{
    __shared__ char sWxT[128 * 256];   // [j][k] bf16, swizzled: 32 KB
    __shared__ char sWeT[128 * 64];    // [j][k] bf16, swizzled:  8 KB

    int tid = threadIdx.x;
    int lane = tid & 63, w = tid >> 6;
    int col = lane & 15, m = lane >> 4;

    // stage transposed weights (once per block)
    for (int i = tid; i < 128 * 128; i += 512) {
        int k = i >> 7, j = i & 127;
        *(short*)(sWxT + j * 256 + ((k * 2) ^ ((j & 7) << 4))) = f2bf(Wx[i]);
    }
    for (int i = tid; i < 32 * 128; i += 512) {
        int k = i >> 7, j = i & 127;
        *(short*)(sWeT + j * 64 + ((k * 2) ^ ((j & 3) << 4))) = f2bf(We[i]);
    }
    float bxv[8], bev[8];
    #pragma unroll
    for (int ct = 0; ct < 8; ++ct) {
        bxv[ct] = bx[ct * 16 + col];
        bev[ct] = be[ct * 16 + col];
    }
    __syncthreads();

    for (int t = blockIdx.x; t < ntiles; t += gridDim.x) {
        int rbase = (t << 7) + (w << 4);
        int lrow = rbase + col;                 // A-frag row for this lane
        bool rok = lrow < N;

        // x A-frags (kk=0..3): each element read exactly once
        const float* xr = x + (size_t)lrow * 128 + m * 8;
        bf16x8 ax[4];
        #pragma unroll
        for (int kk = 0; kk < 4; ++kk) {
            float4 p0 = {0.f, 0.f, 0.f, 0.f}, p1 = {0.f, 0.f, 0.f, 0.f};
            if (rok) {
                p0 = *(const float4*)(xr + kk * 32);
                p1 = *(const float4*)(xr + kk * 32 + 4);
            }
            bf16x8 a;
            a[0] = f2bf(p0.x); a[1] = f2bf(p0.y); a[2] = f2bf(p0.z); a[3] = f2bf(p0.w);
            a[4] = f2bf(p1.x); a[5] = f2bf(p1.y); a[6] = f2bf(p1.z); a[7] = f2bf(p1.w);
            ax[kk] = a;
        }
        // agg A-frag (bf16 direct, 16B load)
        bf16x8 aa = {0, 0, 0, 0, 0, 0, 0, 0};
        if (rok) aa = *(const bf16x8*)(aggbf + (size_t)lrow * 32 + m * 8);

        int srow = rbase + m * 4;

        #pragma unroll
        for (int half = 0; half < 2; ++half) {
            f32x4 acc[8];
            #pragma unroll
            for (int ct = 0; ct < 4; ++ct) {
                int c8 = half * 4 + ct;
                acc[ct]     = (f32x4){bxv[c8], bxv[c8], bxv[c8], bxv[c8]};
                acc[4 + ct] = (f32x4){bev[c8], bev[c8], bev[c8], bev[c8]};
            }

            #pragma unroll
            for (int ct = 0; ct < 4; ++ct) {
                int c8 = half * 4 + ct;
                const char* brow = sWxT + (c8 * 16 + col) * 256;
                int swz = (col & 7) << 4;
                #pragma unroll
                for (int kk = 0; kk < 4; ++kk) {
                    bf16x8 bfrag = *(const bf16x8*)(brow + ((kk * 64 + m * 16) ^ swz));
                    acc[ct] = __builtin_amdgcn_mfma_f32_16x16x32_bf16(ax[kk], bfrag, acc[ct], 0, 0, 0);
                }
                bf16x8 bwe = *(const bf16x8*)(sWeT + (c8 * 16 + col) * 64 + ((m * 16) ^ ((col & 3) << 4)));
                acc[4 + ct] = __builtin_amdgcn_mfma_f32_16x16x32_bf16(aa, bwe, acc[4 + ct], 0, 0, 0);
            }

            // store: C/D row = m*4 + r, col = col + 16*(half*4+ct)
            #pragma unroll
            for (int r = 0; r < 4; ++r) {
                if (srow + r < N) {
                    float* orow = out + (size_t)(srow + r) * 256 + col + half * 64;
                    #pragma unroll
                    for (int ct = 0; ct < 4; ++ct) {
                        orow[ct * 16]       = acc[ct][r];
                        orow[128 + ct * 16] = acc[4 + ct][r];
                    }
                }
            }
        }
    }
}

extern "C" void kernel_launch(void* const* d_in, const int* in_sizes, int n_in,
                              void* d_out, int out_size, void* d_ws, size_t ws_size,
                              hipStream_t stream) {
    const float* x          = (const float*)d_in[0];
    const int*   edge_index = (const int*)d_in[1];   // [2,E] flat; row 0 = src
    const float* edge_attr  = (const float*)d_in[2];
    const float* Wx         = (const float*)d_in[3];
    const float* bx         = (const float*)d_in[4];
    const float* We         = (const float*)d_in[5];
    const float* be         = (const float*)d_in[6];
    float* out = (float*)d_out;

    int N = in_sizes[0] / 128;
    int E = in_sizes[2] / 32;
    int nb = (N + BSIZE - 1) >> BSHIFT;
    int ntiles = (N + 127) >> 7;

    char* ws = (char*)d_ws;
    size_t aggbfBytes = ((size_t)N * 32 * 2 + 255) & ~255ull;
    size_t segsBytes  = ((size_t)nb * SEG_CAP * 4 + 255) & ~255ull;
    size_t gcntBytes  = ((size_t)(nb + 1) * 4 + 255) & ~255ull;
    size_t spillBytes = (size_t)SPILL_CAP * 8;
    size_t need = aggbfBytes + segsBytes + gcntBytes + spillBytes;

    unsigned short* aggbf = (unsigned short*)ws;

    if (ws_size >= need && nb <= NBMAX) {
        unsigned* segs  = (unsigned*)(ws + aggbfBytes);
        int* gcnt       = (int*)(ws + aggbfBytes + segsBytes);
        int* spillcnt   = gcnt + nb;
        int2* spill     = (int2*)(ws + aggbfBytes + segsBytes + gcntBytes);

        hipMemsetAsync(gcnt, 0, (size_t)(nb + 1) * 4, stream);
        int nblkA = (E + CHUNK_A - 1) / CHUNK_A;
        binA_kernel<<<nblkA, 256, 0, stream>>>(edge_index, E, nb, segs, gcnt, spill, spillcnt);
        gather_kernel<<<nb, 512, 0, stream>>>(segs, gcnt, spill, spillcnt,
                                              (const float4*)edge_attr, aggbf, N);
    } else {
        float* aggf = (float*)(ws + aggbfBytes);
        hipMemsetAsync(aggf, 0, (size_t)N * 32 * 4, stream);
        int nq = E * 8;
        scatter_kernel<<<(nq + 255) / 256, 256, 0, stream>>>(
            (const float4*)edge_attr, edge_index, aggf, nq);
        cvt_kernel<<<(N * 32 + 255) / 256, 256, 0, stream>>>(aggf, aggbf, N * 32);
    }

    mfma_gemm<<<ntiles, 512, 0, stream>>>(x, aggbf, Wx, bx, We, be, out, N, ntiles);
}

// Round 7
// 205.026 us; speedup vs baseline: 2.7336x; 2.7336x over previous
//
#include <hip/hip_runtime.h>

// out[N,256] = concat( x[N,128] @ Wx[128,128] + bx,
//                      segsum(edge_attr by src)[N,32] @ We[32,128] + be )
//
// Pipeline:
//   binA:   bucket packed (edge_id<<7 | node&127) by src>>7 (128-node buckets)
//   gather: per bucket, local CSR in LDS (count/scan/fill), then per-node
//           register-accumulate gather (4-deep MLP), bf16 flush
//   gemm:   MFMA bf16 16x16x32; weights AND x/agg tiles staged in swizzled
//           LDS with coalesced loads; persistent grid.

#define BSHIFT    7
#define BSIZE     128
#define NBMAX     1024
#define SEG_CAP   3584    // pairs per bucket (mean ~2046, sigma ~45, +34 sigma)
#define POOL_SZ   3648
#define CHUNK_A   8192
#define SPILL_CAP 65536

typedef short bf16x8 __attribute__((ext_vector_type(8)));
typedef float f32x4  __attribute__((ext_vector_type(4)));

__device__ __forceinline__ unsigned short f2bf(float f) {
    union { float f; unsigned u; } c; c.f = f;
    unsigned u = c.u;
    u += 0x7FFF + ((u >> 16) & 1);          // round-to-nearest-even
    return (unsigned short)(u >> 16);
}

// ---------- Pass A: bucket edges (packed 4B pairs) ----------
__global__ __launch_bounds__(256) void binA_kernel(
    const int* __restrict__ src, int E, int nb,
    unsigned* __restrict__ segs, int* __restrict__ gcnt,
    int2* __restrict__ spill, int* __restrict__ spillcnt)
{
    __shared__ unsigned pool[CHUNK_A];      // 32 KB
    __shared__ int hist[NBMAX];
    __shared__ int offs[NBMAX];
    __shared__ int lcur[NBMAX];
    __shared__ int gbase[NBMAX];
    __shared__ int gallow[NBMAX];
    __shared__ int wsum[4];

    int tid = threadIdx.x;
    int base = blockIdx.x * CHUNK_A;

    for (int i = tid; i < NBMAX; i += 256) hist[i] = 0;
    __syncthreads();

    for (int i = tid; i < CHUNK_A; i += 256) {
        int e = base + i;
        if (e < E) atomicAdd(&hist[src[e] >> BSHIFT], 1);
    }
    __syncthreads();

    // block exclusive scan: each thread owns buckets 4t..4t+3
    {
        int t4 = tid * 4;
        int c0 = hist[t4], c1 = hist[t4 + 1], c2 = hist[t4 + 2], c3 = hist[t4 + 3];
        int s = c0 + c1 + c2 + c3;
        int lane = tid & 63, wid = tid >> 6;
        int ws = s;
        #pragma unroll
        for (int d = 1; d < 64; d <<= 1) {
            int t = __shfl_up(ws, d);
            if (lane >= d) ws += t;
        }
        if (lane == 63) wsum[wid] = ws;
        __syncthreads();
        int woff = 0;
        #pragma unroll
        for (int w = 0; w < 4; ++w) if (w < wid) woff += wsum[w];
        int ex = woff + ws - s;
        offs[t4] = ex;               lcur[t4] = ex;
        offs[t4 + 1] = ex + c0;      lcur[t4 + 1] = ex + c0;
        offs[t4 + 2] = ex + c0 + c1; lcur[t4 + 2] = ex + c0 + c1;
        offs[t4 + 3] = ex + c0 + c1 + c2; lcur[t4 + 3] = ex + c0 + c1 + c2;
    }
    __syncthreads();

    // reserve global segment space
    {
        int t4 = tid * 4;
        #pragma unroll
        for (int u = 0; u < 4; ++u) {
            int b = t4 + u;
            if (b < nb) {
                int cnt = hist[b];
                int b0 = cnt ? atomicAdd(&gcnt[b], cnt) : 0;
                gbase[b] = b0;
                int allow = SEG_CAP - b0;
                if (allow < 0) allow = 0;
                if (allow > cnt) allow = cnt;
                gallow[b] = allow;
            }
        }
    }
    __syncthreads();

    // place packed pairs into LDS pool grouped by bucket
    for (int i = tid; i < CHUNK_A; i += 256) {
        int e = base + i;
        if (e < E) {
            int s = src[e];
            int b = s >> BSHIFT;
            int p = atomicAdd(&lcur[b], 1);
            pool[p] = ((unsigned)e << BSHIFT) | (unsigned)(s & (BSIZE - 1));
        }
    }
    __syncthreads();

    // coalesced flush
    int wid = tid >> 6, lane = tid & 63;
    for (int b = wid; b < nb; b += 4) {
        int cnt = hist[b];
        int off = offs[b];
        int allow = gallow[b];
        unsigned* dst = segs + (size_t)b * SEG_CAP + gbase[b];
        for (int i = lane; i < allow; i += 64)
            dst[i] = pool[off + i];
        int excess = cnt - allow;
        if (excess > 0) {                 // never in practice
            int sb;
            if (lane == 0) sb = atomicAdd(spillcnt, excess);
            sb = __shfl(sb, 0);
            for (int i = lane; i < excess; i += 64) {
                int sp = sb + i;
                if (sp < SPILL_CAP) {
                    unsigned pv = pool[off + allow + i];
                    spill[sp] = make_int2((int)(pv >> BSHIFT),
                                          (b << BSHIFT) | (int)(pv & (BSIZE - 1)));
                }
            }
        }
    }
}

// ---------- gather: local CSR in LDS, register accumulate ----------
__global__ __launch_bounds__(512) void gather_kernel(
    const unsigned* __restrict__ segs, const int* __restrict__ gcnt,
    const int2* __restrict__ spill, const int* __restrict__ spillcnt,
    const float4* __restrict__ ea4, unsigned short* __restrict__ aggbf, int N)
{
    __shared__ int counts[BSIZE];
    __shared__ int starts[BSIZE + 1];
    __shared__ int cursor[BSIZE];
    __shared__ int pool[POOL_SZ];       // ~14.6 KB edge ids

    int tid = threadIdx.x;
    int b = blockIdx.x;
    int node0 = b << BSHIFT;

    if (tid < BSIZE) counts[tid] = 0;
    __syncthreads();

    int segn = gcnt[b]; if (segn > SEG_CAP) segn = SEG_CAP;
    const unsigned* seg = segs + (size_t)b * SEG_CAP;
    int nsp = *spillcnt; if (nsp > SPILL_CAP) nsp = SPILL_CAP;

    // count
    for (int i = tid; i < segn; i += 512)
        atomicAdd(&counts[seg[i] & (BSIZE - 1)], 1);
    if (nsp)
        for (int i = tid; i < nsp; i += 512) {
            int2 p = spill[i];
            if ((p.y >> BSHIFT) == b) atomicAdd(&counts[p.y & (BSIZE - 1)], 1);
        }
    __syncthreads();

    // exclusive scan over 128 counters (wave 0, 2 per lane)
    if (tid < 64) {
        int c0 = counts[tid * 2], c1 = counts[tid * 2 + 1];
        int s = c0 + c1;
        int ws = s;
        #pragma unroll
        for (int d = 1; d < 64; d <<= 1) {
            int t = __shfl_up(ws, d);
            if (tid >= d) ws += t;
        }
        int ex = ws - s;
        starts[tid * 2] = ex;          cursor[tid * 2] = ex;
        starts[tid * 2 + 1] = ex + c0; cursor[tid * 2 + 1] = ex + c0;
        if (tid == 63) starts[BSIZE] = ws;
    }
    __syncthreads();

    // fill local CSR pool with edge ids
    for (int i = tid; i < segn; i += 512) {
        unsigned pe = seg[i];
        int pos = atomicAdd(&cursor[pe & (BSIZE - 1)], 1);
        if (pos < POOL_SZ) pool[pos] = (int)(pe >> BSHIFT);
    }
    if (nsp)
        for (int i = tid; i < nsp; i += 512) {
            int2 p = spill[i];
            if ((p.y >> BSHIFT) == b) {
                int pos = atomicAdd(&cursor[p.y & (BSIZE - 1)], 1);
                if (pos < POOL_SZ) pool[pos] = p.x;
            }
        }
    __syncthreads();

    // per-node register gather: 8 threads/node, 64 nodes/pass
    int g = tid >> 3, q = tid & 7;
    #pragma unroll
    for (int pass = 0; pass < 2; ++pass) {
        int nl = pass * 64 + g;
        int node = node0 + nl;
        if (node >= N) continue;
        int p0 = starts[nl], p1 = starts[nl + 1];
        if (p1 > POOL_SZ) p1 = POOL_SZ;
        float4 a0 = {0.f, 0.f, 0.f, 0.f};
        float4 a1 = {0.f, 0.f, 0.f, 0.f};
        int p = p0;
        for (; p + 4 <= p1; p += 4) {           // 4 lines in flight
            int e0 = pool[p], e1 = pool[p + 1], e2 = pool[p + 2], e3 = pool[p + 3];
            float4 v0 = ea4[(size_t)e0 * 8 + q];
            float4 v1 = ea4[(size_t)e1 * 8 + q];
            float4 v2 = ea4[(size_t)e2 * 8 + q];
            float4 v3 = ea4[(size_t)e3 * 8 + q];
            a0.x += v0.x; a0.y += v0.y; a0.z += v0.z; a0.w += v0.w;
            a1.x += v1.x; a1.y += v1.y; a1.z += v1.z; a1.w += v1.w;
            a0.x += v2.x; a0.y += v2.y; a0.z += v2.z; a0.w += v2.w;
            a1.x += v3.x; a1.y += v3.y; a1.z += v3.z; a1.w += v3.w;
        }
        for (; p < p1; ++p) {
            float4 v = ea4[(size_t)pool[p] * 8 + q];
            a0.x += v.x; a0.y += v.y; a0.z += v.z; a0.w += v.w;
        }
        a0.x += a1.x; a0.y += a1.y; a0.z += a1.z; a0.w += a1.w;
        unsigned u0 = (unsigned)f2bf(a0.x) | ((unsigned)f2bf(a0.y) << 16);
        unsigned u1 = (unsigned)f2bf(a0.z) | ((unsigned)f2bf(a0.w) << 16);
        uint2 uu; uu.x = u0; uu.y = u1;
        *(uint2*)(aggbf + (size_t)node * 32 + q * 4) = uu;   // 8B coalesced
    }
}

// ---------- fallback: atomic scatter + convert ----------
__global__ __launch_bounds__(256) void scatter_kernel(
    const float4* __restrict__ ea4, const int* __restrict__ src,
    float* __restrict__ agg, int nquads)
{
    int t = blockIdx.x * blockDim.x + threadIdx.x;
    if (t >= nquads) return;
    int e = t >> 3, q = t & 7;
    float4 v = ea4[t];
    int node = src[e];
    float* dst = agg + (size_t)node * 32 + q * 4;
    atomicAdd(dst + 0, v.x); atomicAdd(dst + 1, v.y);
    atomicAdd(dst + 2, v.z); atomicAdd(dst + 3, v.w);
}

__global__ __launch_bounds__(256) void cvt_kernel(
    const float* __restrict__ agg, unsigned short* __restrict__ aggbf, int n)
{
    int t = blockIdx.x * blockDim.x + threadIdx.x;
    if (t < n) aggbf[t] = f2bf(agg[t]);
}

// ---------- MFMA bf16 fused dual-GEMM, all operands LDS-staged ----------
// 512 threads = 8 waves; wave w computes rows [t*128 + w*16, +16) x 256 cols.
__global__ __launch_bounds__(512, 4) void mfma_gemm(
    const float* __restrict__ x, const unsigned short* __restrict__ aggbf,
    const float* __restrict__ Wx, const float* __restrict__ bx,
    const float* __restrict__ We, const float* __restrict__ be,
    float* __restrict__ out, int N, int ntiles)
{
    __shared__ char sWxT[128 * 256];   // Wx^T [j][k] bf16, swizzled: 32 KB
    __shared__ char sWeT[128 * 64];    // We^T [j][k] bf16, swizzled:  8 KB
    __shared__ char sX[128 * 256];     // x-tile [r][k] bf16, swizzled: 32 KB
    __shared__ char sA[128 * 64];      // agg-tile [r][k] bf16, swizzled: 8 KB

    int tid = threadIdx.x;
    int lane = tid & 63, w = tid >> 6;
    int col = lane & 15, m = lane >> 4;

    // stage transposed weights (once per block)
    for (int i = tid; i < 128 * 128; i += 512) {
        int k = i >> 7, j = i & 127;
        *(unsigned short*)(sWxT + j * 256 + ((k * 2) ^ ((j & 7) << 4))) = f2bf(Wx[i]);
    }
    for (int i = tid; i < 32 * 128; i += 512) {
        int k = i >> 7, j = i & 127;
        *(unsigned short*)(sWeT + j * 64 + ((k * 2) ^ ((j & 3) << 4))) = f2bf(We[i]);
    }
    float bxv[8], bev[8];
    #pragma unroll
    for (int ct = 0; ct < 8; ++ct) {
        bxv[ct] = bx[ct * 16 + col];
        bev[ct] = be[ct * 16 + col];
    }

    int lrow = (w << 4) + col;          // tile-local A row this lane consumes
    int swzA = (lrow & 7) << 4;

    for (int t = blockIdx.x; t < ntiles; t += gridDim.x) {
        int rbase_t = t << 7;
        __syncthreads();                // protect prev-iter reads (and weights, 1st iter)

        // stage x-tile: coalesced float4 reads, swizzled bf16 LDS writes
        for (int i = tid; i < 128 * 32; i += 512) {
            int row = i >> 5, c4 = i & 31;
            int gr = rbase_t + row;
            float4 v = {0.f, 0.f, 0.f, 0.f};
            if (gr < N) v = *(const float4*)(x + (size_t)gr * 128 + c4 * 4);
            uint2 uu;
            uu.x = (unsigned)f2bf(v.x) | ((unsigned)f2bf(v.y) << 16);
            uu.y = (unsigned)f2bf(v.z) | ((unsigned)f2bf(v.w) << 16);
            *(uint2*)(sX + ((row * 256 + c4 * 8) ^ ((row & 7) << 4))) = uu;
        }
        // stage agg-tile: 512 x 16B coalesced
        {
            int row = tid >> 2, mm = tid & 3;
            int gr = rbase_t + row;
            bf16x8 av = {0, 0, 0, 0, 0, 0, 0, 0};
            if (gr < N) av = *(const bf16x8*)(aggbf + (size_t)gr * 32 + mm * 8);
            *(bf16x8*)(sA + ((row * 64 + mm * 16) ^ ((row & 7) << 4))) = av;
        }
        __syncthreads();

        // A fragments from LDS
        bf16x8 ax[4];
        #pragma unroll
        for (int kk = 0; kk < 4; ++kk)
            ax[kk] = *(const bf16x8*)(sX + lrow * 256 + ((kk * 64 + m * 16) ^ swzA));
        bf16x8 aa = *(const bf16x8*)(sA + ((lrow * 64 + m * 16) ^ swzA));

        int srow = rbase_t + (w << 4) + m * 4;

        #pragma unroll
        for (int half = 0; half < 2; ++half) {
            f32x4 acc[8];
            #pragma unroll
            for (int ct = 0; ct < 4; ++ct) {
                int c8 = half * 4 + ct;
                acc[ct]     = (f32x4){bxv[c8], bxv[c8], bxv[c8], bxv[c8]};
                acc[4 + ct] = (f32x4){bev[c8], bev[c8], bev[c8], bev[c8]};
            }

            #pragma unroll
            for (int ct = 0; ct < 4; ++ct) {
                int c8 = half * 4 + ct;
                const char* brow = sWxT + (c8 * 16 + col) * 256;
                int swz = (col & 7) << 4;
                #pragma unroll
                for (int kk = 0; kk < 4; ++kk) {
                    bf16x8 bfrag = *(const bf16x8*)(brow + ((kk * 64 + m * 16) ^ swz));
                    acc[ct] = __builtin_amdgcn_mfma_f32_16x16x32_bf16(ax[kk], bfrag, acc[ct], 0, 0, 0);
                }
                bf16x8 bwe = *(const bf16x8*)(sWeT + (c8 * 16 + col) * 64 + ((m * 16) ^ ((col & 3) << 4)));
                acc[4 + ct] = __builtin_amdgcn_mfma_f32_16x16x32_bf16(aa, bwe, acc[4 + ct], 0, 0, 0);
            }

            #pragma unroll
            for (int r = 0; r < 4; ++r) {
                if (srow + r < N) {
                    float* orow = out + (size_t)(srow + r) * 256 + col + half * 64;
                    #pragma unroll
                    for (int ct = 0; ct < 4; ++ct) {
                        orow[ct * 16]       = acc[ct][r];
                        orow[128 + ct * 16] = acc[4 + ct][r];
                    }
                }
            }
        }
    }
}

extern "C" void kernel_launch(void* const* d_in, const int* in_sizes, int n_in,
                              void* d_out, int out_size, void* d_ws, size_t ws_size,
                              hipStream_t stream) {
    const float* x          = (const float*)d_in[0];
    const int*   edge_index = (const int*)d_in[1];   // [2,E] flat; row 0 = src
    const float* edge_attr  = (const float*)d_in[2];
    const float* Wx         = (const float*)d_in[3];
    const float* bx         = (const float*)d_in[4];
    const float* We         = (const float*)d_in[5];
    const float* be         = (const float*)d_in[6];
    float* out = (float*)d_out;

    int N = in_sizes[0] / 128;
    int E = in_sizes[2] / 32;
    int nb = (N + BSIZE - 1) >> BSHIFT;
    int ntiles = (N + 127) >> 7;

    char* ws = (char*)d_ws;
    size_t aggbfBytes = ((size_t)N * 32 * 2 + 255) & ~255ull;
    size_t segsBytes  = ((size_t)nb * SEG_CAP * 4 + 255) & ~255ull;
    size_t gcntBytes  = ((size_t)(nb + 1) * 4 + 255) & ~255ull;
    size_t spillBytes = (size_t)SPILL_CAP * 8;
    size_t need = aggbfBytes + segsBytes + gcntBytes + spillBytes;

    unsigned short* aggbf = (unsigned short*)ws;

    if (ws_size >= need && nb <= NBMAX) {
        unsigned* segs  = (unsigned*)(ws + aggbfBytes);
        int* gcnt       = (int*)(ws + aggbfBytes + segsBytes);
        int* spillcnt   = gcnt + nb;
        int2* spill     = (int2*)(ws + aggbfBytes + segsBytes + gcntBytes);

        hipMemsetAsync(gcnt, 0, (size_t)(nb + 1) * 4, stream);
        int nblkA = (E + CHUNK_A - 1) / CHUNK_A;
        binA_kernel<<<nblkA, 256, 0, stream>>>(edge_index, E, nb, segs, gcnt, spill, spillcnt);
        gather_kernel<<<nb, 512, 0, stream>>>(segs, gcnt, spill, spillcnt,
                                              (const float4*)edge_attr, aggbf, N);
    } else {
        float* aggf = (float*)(ws + aggbfBytes);
        hipMemsetAsync(aggf, 0, (size_t)N * 32 * 4, stream);
        int nq = E * 8;
        scatter_kernel<<<(nq + 255) / 256, 256, 0, stream>>>(
            (const float4*)edge_attr, edge_index, aggf, nq);
        cvt_kernel<<<(N * 32 + 255) / 256, 256, 0, stream>>>(aggf, aggbf, N * 32);
    }

    int g = ntiles < 512 ? ntiles : 512;
    mfma_gemm<<<g, 512, 0, stream>>>(x, aggbf, Wx, bx, We, be, out, N, ntiles);
}

// Round 8
// 170.975 us; speedup vs baseline: 3.2780x; 1.1992x over previous
//
#include <hip/hip_runtime.h>

// out[N,256] = concat( x[N,128] @ Wx[128,128] + bx,
//                      segsum(edge_attr by src)[N,32] @ We[32,128] + be )
//
// Pipeline:
//   binA:   bucket packed (edge_id<<7 | node&127) by src>>7 (128-node buckets)
//   gather: per bucket, local CSR in LDS, then per-node register gather with
//           4 threads/node x 2 quads x 4-deep unroll (8 loads in flight)
//   gemm:   MFMA bf16 16x16x32; weights AND x/agg tiles staged in swizzled LDS.

#define BSHIFT    7
#define BSIZE     128
#define NBMAX     1024
#define SEG_CAP   3584    // pairs per bucket (mean ~2046, sigma ~45, +34 sigma)
#define POOL_SZ   3648
#define CHUNK_A   8192
#define SPILL_CAP 65536

typedef short bf16x8 __attribute__((ext_vector_type(8)));
typedef float f32x4  __attribute__((ext_vector_type(4)));

__device__ __forceinline__ unsigned short f2bf(float f) {
    union { float f; unsigned u; } c; c.f = f;
    unsigned u = c.u;
    u += 0x7FFF + ((u >> 16) & 1);          // round-to-nearest-even
    return (unsigned short)(u >> 16);
}

// ---------- Pass A: bucket edges (packed 4B pairs) ----------
__global__ __launch_bounds__(512) void binA_kernel(
    const int* __restrict__ src, int E, int nb,
    unsigned* __restrict__ segs, int* __restrict__ gcnt,
    int2* __restrict__ spill, int* __restrict__ spillcnt)
{
    __shared__ unsigned pool[CHUNK_A];      // 32 KB
    __shared__ int hist[NBMAX];
    __shared__ int offs[NBMAX];
    __shared__ int lcur[NBMAX];
    __shared__ int gbase[NBMAX];
    __shared__ int gallow[NBMAX];
    __shared__ int wsum[8];

    int tid = threadIdx.x;
    int base = blockIdx.x * CHUNK_A;

    for (int i = tid; i < NBMAX; i += 512) hist[i] = 0;
    __syncthreads();

    for (int i = tid; i < CHUNK_A; i += 512) {
        int e = base + i;
        if (e < E) atomicAdd(&hist[src[e] >> BSHIFT], 1);
    }
    __syncthreads();

    // block exclusive scan: each thread owns buckets 2t, 2t+1
    {
        int t2 = tid * 2;
        int c0 = hist[t2], c1 = hist[t2 + 1];
        int s = c0 + c1;
        int lane = tid & 63, wid = tid >> 6;
        int ws = s;
        #pragma unroll
        for (int d = 1; d < 64; d <<= 1) {
            int t = __shfl_up(ws, d);
            if (lane >= d) ws += t;
        }
        if (lane == 63) wsum[wid] = ws;
        __syncthreads();
        int woff = 0;
        #pragma unroll
        for (int w = 0; w < 8; ++w) if (w < wid) woff += wsum[w];
        int ex = woff + ws - s;
        offs[t2] = ex;          lcur[t2] = ex;
        offs[t2 + 1] = ex + c0; lcur[t2 + 1] = ex + c0;
    }
    __syncthreads();

    // reserve global segment space
    {
        int t2 = tid * 2;
        #pragma unroll
        for (int u = 0; u < 2; ++u) {
            int b = t2 + u;
            if (b < nb) {
                int cnt = hist[b];
                int b0 = cnt ? atomicAdd(&gcnt[b], cnt) : 0;
                gbase[b] = b0;
                int allow = SEG_CAP - b0;
                if (allow < 0) allow = 0;
                if (allow > cnt) allow = cnt;
                gallow[b] = allow;
            }
        }
    }
    __syncthreads();

    // place packed pairs into LDS pool grouped by bucket
    for (int i = tid; i < CHUNK_A; i += 512) {
        int e = base + i;
        if (e < E) {
            int s = src[e];
            int b = s >> BSHIFT;
            int p = atomicAdd(&lcur[b], 1);
            pool[p] = ((unsigned)e << BSHIFT) | (unsigned)(s & (BSIZE - 1));
        }
    }
    __syncthreads();

    // coalesced flush: wave w handles buckets w, w+8, ...
    int wid = tid >> 6, lane = tid & 63;
    for (int b = wid; b < nb; b += 8) {
        int cnt = hist[b];
        int off = offs[b];
        int allow = gallow[b];
        unsigned* dst = segs + (size_t)b * SEG_CAP + gbase[b];
        for (int i = lane; i < allow; i += 64)
            dst[i] = pool[off + i];
        int excess = cnt - allow;
        if (excess > 0) {                 // never in practice
            int sb;
            if (lane == 0) sb = atomicAdd(spillcnt, excess);
            sb = __shfl(sb, 0);
            for (int i = lane; i < excess; i += 64) {
                int sp = sb + i;
                if (sp < SPILL_CAP) {
                    unsigned pv = pool[off + allow + i];
                    spill[sp] = make_int2((int)(pv >> BSHIFT),
                                          (b << BSHIFT) | (int)(pv & (BSIZE - 1)));
                }
            }
        }
    }
}

// ---------- gather: local CSR in LDS, 8-deep register accumulate ----------
__global__ __launch_bounds__(512) void gather_kernel(
    const unsigned* __restrict__ segs, const int* __restrict__ gcnt,
    const int2* __restrict__ spill, const int* __restrict__ spillcnt,
    const float4* __restrict__ ea4, unsigned short* __restrict__ aggbf, int N)
{
    __shared__ int counts[BSIZE];
    __shared__ int starts[BSIZE + 1];
    __shared__ int cursor[BSIZE];
    __shared__ int pool[POOL_SZ];       // ~14.6 KB edge ids

    int tid = threadIdx.x;
    int b = blockIdx.x;
    int node0 = b << BSHIFT;

    if (tid < BSIZE) counts[tid] = 0;
    __syncthreads();

    int segn = gcnt[b]; if (segn > SEG_CAP) segn = SEG_CAP;
    const unsigned* seg = segs + (size_t)b * SEG_CAP;
    int nsp = *spillcnt; if (nsp > SPILL_CAP) nsp = SPILL_CAP;

    // count
    for (int i = tid; i < segn; i += 512)
        atomicAdd(&counts[seg[i] & (BSIZE - 1)], 1);
    if (nsp)
        for (int i = tid; i < nsp; i += 512) {
            int2 p = spill[i];
            if ((p.y >> BSHIFT) == b) atomicAdd(&counts[p.y & (BSIZE - 1)], 1);
        }
    __syncthreads();

    // exclusive scan over 128 counters (wave 0, 2 per lane)
    if (tid < 64) {
        int c0 = counts[tid * 2], c1 = counts[tid * 2 + 1];
        int s = c0 + c1;
        int ws = s;
        #pragma unroll
        for (int d = 1; d < 64; d <<= 1) {
            int t = __shfl_up(ws, d);
            if (tid >= d) ws += t;
        }
        int ex = ws - s;
        starts[tid * 2] = ex;          cursor[tid * 2] = ex;
        starts[tid * 2 + 1] = ex + c0; cursor[tid * 2 + 1] = ex + c0;
        if (tid == 63) starts[BSIZE] = ws;
    }
    __syncthreads();

    // fill local CSR pool with edge ids
    for (int i = tid; i < segn; i += 512) {
        unsigned pe = seg[i];
        int pos = atomicAdd(&cursor[pe & (BSIZE - 1)], 1);
        if (pos < POOL_SZ) pool[pos] = (int)(pe >> BSHIFT);
    }
    if (nsp)
        for (int i = tid; i < nsp; i += 512) {
            int2 p = spill[i];
            if ((p.y >> BSHIFT) == b) {
                int pos = atomicAdd(&cursor[p.y & (BSIZE - 1)], 1);
                if (pos < POOL_SZ) pool[pos] = p.x;
            }
        }
    __syncthreads();

    // per-node register gather: 4 threads/node, quads q2 and q2+4,
    // 4-deep unroll => 8 independent loads in flight per thread.
    int g = tid >> 2, q2 = tid & 3;
    int node = node0 + g;
    if (node < N) {
        int p0 = starts[g], p1 = starts[g + 1];
        if (p1 > POOL_SZ) p1 = POOL_SZ;
        float4 aL0 = {0.f,0.f,0.f,0.f}, aL1 = {0.f,0.f,0.f,0.f};
        float4 aH0 = {0.f,0.f,0.f,0.f}, aH1 = {0.f,0.f,0.f,0.f};
        int p = p0;
        for (; p + 4 <= p1; p += 4) {
            int e0 = pool[p], e1 = pool[p + 1], e2 = pool[p + 2], e3 = pool[p + 3];
            const float4* r0 = ea4 + (size_t)e0 * 8;
            const float4* r1 = ea4 + (size_t)e1 * 8;
            const float4* r2 = ea4 + (size_t)e2 * 8;
            const float4* r3 = ea4 + (size_t)e3 * 8;
            float4 l0 = r0[q2],     l1 = r1[q2],     l2 = r2[q2],     l3 = r3[q2];
            float4 h0 = r0[q2 + 4], h1 = r1[q2 + 4], h2 = r2[q2 + 4], h3 = r3[q2 + 4];
            aL0.x += l0.x; aL0.y += l0.y; aL0.z += l0.z; aL0.w += l0.w;
            aL1.x += l1.x; aL1.y += l1.y; aL1.z += l1.z; aL1.w += l1.w;
            aH0.x += h0.x; aH0.y += h0.y; aH0.z += h0.z; aH0.w += h0.w;
            aH1.x += h1.x; aH1.y += h1.y; aH1.z += h1.z; aH1.w += h1.w;
            aL0.x += l2.x; aL0.y += l2.y; aL0.z += l2.z; aL0.w += l2.w;
            aL1.x += l3.x; aL1.y += l3.y; aL1.z += l3.z; aL1.w += l3.w;
            aH0.x += h2.x; aH0.y += h2.y; aH0.z += h2.z; aH0.w += h2.w;
            aH1.x += h3.x; aH1.y += h3.y; aH1.z += h3.z; aH1.w += h3.w;
        }
        for (; p < p1; ++p) {
            const float4* r = ea4 + (size_t)pool[p] * 8;
            float4 l = r[q2], h = r[q2 + 4];
            aL0.x += l.x; aL0.y += l.y; aL0.z += l.z; aL0.w += l.w;
            aH0.x += h.x; aH0.y += h.y; aH0.z += h.z; aH0.w += h.w;
        }
        aL0.x += aL1.x; aL0.y += aL1.y; aL0.z += aL1.z; aL0.w += aL1.w;
        aH0.x += aH1.x; aH0.y += aH1.y; aH0.z += aH1.z; aH0.w += aH1.w;
        uint2 lo, hi;
        lo.x = (unsigned)f2bf(aL0.x) | ((unsigned)f2bf(aL0.y) << 16);
        lo.y = (unsigned)f2bf(aL0.z) | ((unsigned)f2bf(aL0.w) << 16);
        hi.x = (unsigned)f2bf(aH0.x) | ((unsigned)f2bf(aH0.y) << 16);
        hi.y = (unsigned)f2bf(aH0.z) | ((unsigned)f2bf(aH0.w) << 16);
        *(uint2*)(aggbf + (size_t)node * 32 + q2 * 4)       = lo;
        *(uint2*)(aggbf + (size_t)node * 32 + (q2 + 4) * 4) = hi;
    }
}

// ---------- fallback: atomic scatter + convert ----------
__global__ __launch_bounds__(256) void scatter_kernel(
    const float4* __restrict__ ea4, const int* __restrict__ src,
    float* __restrict__ agg, int nquads)
{
    int t = blockIdx.x * blockDim.x + threadIdx.x;
    if (t >= nquads) return;
    int e = t >> 3, q = t & 7;
    float4 v = ea4[t];
    int node = src[e];
    float* dst = agg + (size_t)node * 32 + q * 4;
    atomicAdd(dst + 0, v.x); atomicAdd(dst + 1, v.y);
    atomicAdd(dst + 2, v.z); atomicAdd(dst + 3, v.w);
}

__global__ __launch_bounds__(256) void cvt_kernel(
    const float* __restrict__ agg, unsigned short* __restrict__ aggbf, int n)
{
    int t = blockIdx.x * blockDim.x + threadIdx.x;
    if (t < n) aggbf[t] = f2bf(agg[t]);
}

// ---------- MFMA bf16 fused dual-GEMM, all operands LDS-staged ----------
__global__ __launch_bounds__(512, 4) void mfma_gemm(
    const float* __restrict__ x, const unsigned short* __restrict__ aggbf,
    const float* __restrict__ Wx, const float* __restrict__ bx,
    const float* __restrict__ We, const float* __restrict__ be,
    float* __restrict__ out, int N, int ntiles)
{
    __shared__ char sWxT[128 * 256];   // Wx^T [j][k] bf16, swizzled: 32 KB
    __shared__ char sWeT[128 * 64];    // We^T [j][k] bf16, swizzled:  8 KB
    __shared__ char sX[128 * 256];     // x-tile [r][k] bf16, swizzled: 32 KB
    __shared__ char sA[128 * 64];      // agg-tile [r][k] bf16, swizzled: 8 KB

    int tid = threadIdx.x;
    int lane = tid & 63, w = tid >> 6;
    int col = lane & 15, m = lane >> 4;

    // stage transposed weights (once per block)
    for (int i = tid; i < 128 * 128; i += 512) {
        int k = i >> 7, j = i & 127;
        *(unsigned short*)(sWxT + j * 256 + ((k * 2) ^ ((j & 7) << 4))) = f2bf(Wx[i]);
    }
    for (int i = tid; i < 32 * 128; i += 512) {
        int k = i >> 7, j = i & 127;
        *(unsigned short*)(sWeT + j * 64 + ((k * 2) ^ ((j & 3) << 4))) = f2bf(We[i]);
    }
    float bxv[8], bev[8];
    #pragma unroll
    for (int ct = 0; ct < 8; ++ct) {
        bxv[ct] = bx[ct * 16 + col];
        bev[ct] = be[ct * 16 + col];
    }

    int lrow = (w << 4) + col;          // tile-local A row this lane consumes
    int swzA = (lrow & 7) << 4;

    for (int t = blockIdx.x; t < ntiles; t += gridDim.x) {
        int rbase_t = t << 7;
        __syncthreads();                // protect prev-iter reads (and weights, 1st iter)

        // stage x-tile: coalesced float4 reads, swizzled bf16 LDS writes
        for (int i = tid; i < 128 * 32; i += 512) {
            int row = i >> 5, c4 = i & 31;
            int gr = rbase_t + row;
            float4 v = {0.f, 0.f, 0.f, 0.f};
            if (gr < N) v = *(const float4*)(x + (size_t)gr * 128 + c4 * 4);
            uint2 uu;
            uu.x = (unsigned)f2bf(v.x) | ((unsigned)f2bf(v.y) << 16);
            uu.y = (unsigned)f2bf(v.z) | ((unsigned)f2bf(v.w) << 16);
            *(uint2*)(sX + ((row * 256 + c4 * 8) ^ ((row & 7) << 4))) = uu;
        }
        // stage agg-tile: 512 x 16B coalesced
        {
            int row = tid >> 2, mm = tid & 3;
            int gr = rbase_t + row;
            bf16x8 av = {0, 0, 0, 0, 0, 0, 0, 0};
            if (gr < N) av = *(const bf16x8*)(aggbf + (size_t)gr * 32 + mm * 8);
            *(bf16x8*)(sA + ((row * 64 + mm * 16) ^ ((row & 7) << 4))) = av;
        }
        __syncthreads();

        // A fragments from LDS
        bf16x8 ax[4];
        #pragma unroll
        for (int kk = 0; kk < 4; ++kk)
            ax[kk] = *(const bf16x8*)(sX + lrow * 256 + ((kk * 64 + m * 16) ^ swzA));
        bf16x8 aa = *(const bf16x8*)(sA + ((lrow * 64 + m * 16) ^ swzA));

        int srow = rbase_t + (w << 4) + m * 4;

        #pragma unroll
        for (int half = 0; half < 2; ++half) {
            f32x4 acc[8];
            #pragma unroll
            for (int ct = 0; ct < 4; ++ct) {
                int c8 = half * 4 + ct;
                acc[ct]     = (f32x4){bxv[c8], bxv[c8], bxv[c8], bxv[c8]};
                acc[4 + ct] = (f32x4){bev[c8], bev[c8], bev[c8], bev[c8]};
            }

            #pragma unroll
            for (int ct = 0; ct < 4; ++ct) {
                int c8 = half * 4 + ct;
                const char* brow = sWxT + (c8 * 16 + col) * 256;
                int swz = (col & 7) << 4;
                #pragma unroll
                for (int kk = 0; kk < 4; ++kk) {
                    bf16x8 bfrag = *(const bf16x8*)(brow + ((kk * 64 + m * 16) ^ swz));
                    acc[ct] = __builtin_amdgcn_mfma_f32_16x16x32_bf16(ax[kk], bfrag, acc[ct], 0, 0, 0);
                }
                bf16x8 bwe = *(const bf16x8*)(sWeT + (c8 * 16 + col) * 64 + ((m * 16) ^ ((col & 3) << 4)));
                acc[4 + ct] = __builtin_amdgcn_mfma_f32_16x16x32_bf16(aa, bwe, acc[4 + ct], 0, 0, 0);
            }

            #pragma unroll
            for (int r = 0; r < 4; ++r) {
                if (srow + r < N) {
                    float* orow = out + (size_t)(srow + r) * 256 + col + half * 64;
                    #pragma unroll
                    for (int ct = 0; ct < 4; ++ct) {
                        orow[ct * 16]       = acc[ct][r];
                        orow[128 + ct * 16] = acc[4 + ct][r];
                    }
                }
            }
        }
    }
}

extern "C" void kernel_launch(void* const* d_in, const int* in_sizes, int n_in,
                              void* d_out, int out_size, void* d_ws, size_t ws_size,
                              hipStream_t stream) {
    const float* x          = (const float*)d_in[0];
    const int*   edge_index = (const int*)d_in[1];   // [2,E] flat; row 0 = src
    const float* edge_attr  = (const float*)d_in[2];
    const float* Wx         = (const float*)d_in[3];
    const float* bx         = (const float*)d_in[4];
    const float* We         = (const float*)d_in[5];
    const float* be         = (const float*)d_in[6];
    float* out = (float*)d_out;

    int N = in_sizes[0] / 128;
    int E = in_sizes[2] / 32;
    int nb = (N + BSIZE - 1) >> BSHIFT;
    int ntiles = (N + 127) >> 7;

    char* ws = (char*)d_ws;
    size_t aggbfBytes = ((size_t)N * 32 * 2 + 255) & ~255ull;
    size_t segsBytes  = ((size_t)nb * SEG_CAP * 4 + 255) & ~255ull;
    size_t gcntBytes  = ((size_t)(nb + 1) * 4 + 255) & ~255ull;
    size_t spillBytes = (size_t)SPILL_CAP * 8;
    size_t need = aggbfBytes + segsBytes + gcntBytes + spillBytes;

    unsigned short* aggbf = (unsigned short*)ws;

    if (ws_size >= need && nb <= NBMAX) {
        unsigned* segs  = (unsigned*)(ws + aggbfBytes);
        int* gcnt       = (int*)(ws + aggbfBytes + segsBytes);
        int* spillcnt   = gcnt + nb;
        int2* spill     = (int2*)(ws + aggbfBytes + segsBytes + gcntBytes);

        hipMemsetAsync(gcnt, 0, (size_t)(nb + 1) * 4, stream);
        int nblkA = (E + CHUNK_A - 1) / CHUNK_A;
        binA_kernel<<<nblkA, 512, 0, stream>>>(edge_index, E, nb, segs, gcnt, spill, spillcnt);
        gather_kernel<<<nb, 512, 0, stream>>>(segs, gcnt, spill, spillcnt,
                                              (const float4*)edge_attr, aggbf, N);
    } else {
        float* aggf = (float*)(ws + aggbfBytes);
        hipMemsetAsync(aggf, 0, (size_t)N * 32 * 4, stream);
        int nq = E * 8;
        scatter_kernel<<<(nq + 255) / 256, 256, 0, stream>>>(
            (const float4*)edge_attr, edge_index, aggf, nq);
        cvt_kernel<<<(N * 32 + 255) / 256, 256, 0, stream>>>(aggf, aggbf, N * 32);
    }

    int g = ntiles < 512 ? ntiles : 512;
    mfma_gemm<<<g, 512, 0, stream>>>(x, aggbf, Wx, bx, We, be, out, N, ntiles);
}

// Round 9
// 150.382 us; speedup vs baseline: 3.7269x; 1.1369x over previous
//
#include <hip/hip_runtime.h>

// out[N,256] = concat( x[N,128] @ Wx[128,128] + bx,
//                      segsum(edge_attr by src)[N,32] @ We[32,128] + be )
//
// Pipeline:
//   binA:       bucket packed (edge_id<<7 | node&127) by src>>7
//   gather_he:  per 128-node bucket: local CSR in LDS -> register gather
//               (4 thr/node, 8 loads in flight) -> agg tile in swizzled LDS
//               -> fused [128,32]@We MFMA -> out[:,128:256]  (no aggbf)
//   hx_gemm:    x @ Wx + bx -> out[:,0:128]  (MFMA bf16, LDS-staged)

#define BSHIFT    7
#define BSIZE     128
#define NBMAX     1024
#define SEG_CAP   3584    // pairs per bucket (mean ~2046, sigma ~45, +34 sigma)
#define POOL_SZ   3648
#define CHUNK_A   8192
#define SPILL_CAP 65536

typedef short bf16x8 __attribute__((ext_vector_type(8)));
typedef float f32x4  __attribute__((ext_vector_type(4)));

__device__ __forceinline__ unsigned short f2bf(float f) {
    union { float f; unsigned u; } c; c.f = f;
    unsigned u = c.u;
    u += 0x7FFF + ((u >> 16) & 1);          // round-to-nearest-even
    return (unsigned short)(u >> 16);
}

// ---------- Pass A: bucket edges (packed 4B pairs) ----------
__global__ __launch_bounds__(512) void binA_kernel(
    const int* __restrict__ src, int E, int nb,
    unsigned* __restrict__ segs, int* __restrict__ gcnt,
    int2* __restrict__ spill, int* __restrict__ spillcnt)
{
    __shared__ unsigned pool[CHUNK_A];      // 32 KB
    __shared__ int hist[NBMAX];
    __shared__ int offs[NBMAX];
    __shared__ int lcur[NBMAX];
    __shared__ int gbase[NBMAX];
    __shared__ int gallow[NBMAX];
    __shared__ int wsum[8];

    int tid = threadIdx.x;
    int base = blockIdx.x * CHUNK_A;

    for (int i = tid; i < NBMAX; i += 512) hist[i] = 0;
    __syncthreads();

    for (int i = tid; i < CHUNK_A; i += 512) {
        int e = base + i;
        if (e < E) atomicAdd(&hist[src[e] >> BSHIFT], 1);
    }
    __syncthreads();

    // block exclusive scan: each thread owns buckets 2t, 2t+1
    {
        int t2 = tid * 2;
        int c0 = hist[t2], c1 = hist[t2 + 1];
        int s = c0 + c1;
        int lane = tid & 63, wid = tid >> 6;
        int ws = s;
        #pragma unroll
        for (int d = 1; d < 64; d <<= 1) {
            int t = __shfl_up(ws, d);
            if (lane >= d) ws += t;
        }
        if (lane == 63) wsum[wid] = ws;
        __syncthreads();
        int woff = 0;
        #pragma unroll
        for (int w = 0; w < 8; ++w) if (w < wid) woff += wsum[w];
        int ex = woff + ws - s;
        offs[t2] = ex;          lcur[t2] = ex;
        offs[t2 + 1] = ex + c0; lcur[t2 + 1] = ex + c0;
    }
    __syncthreads();

    // reserve global segment space
    {
        int t2 = tid * 2;
        #pragma unroll
        for (int u = 0; u < 2; ++u) {
            int b = t2 + u;
            if (b < nb) {
                int cnt = hist[b];
                int b0 = cnt ? atomicAdd(&gcnt[b], cnt) : 0;
                gbase[b] = b0;
                int allow = SEG_CAP - b0;
                if (allow < 0) allow = 0;
                if (allow > cnt) allow = cnt;
                gallow[b] = allow;
            }
        }
    }
    __syncthreads();

    // place packed pairs into LDS pool grouped by bucket
    for (int i = tid; i < CHUNK_A; i += 512) {
        int e = base + i;
        if (e < E) {
            int s = src[e];
            int b = s >> BSHIFT;
            int p = atomicAdd(&lcur[b], 1);
            pool[p] = ((unsigned)e << BSHIFT) | (unsigned)(s & (BSIZE - 1));
        }
    }
    __syncthreads();

    // coalesced flush: wave w handles buckets w, w+8, ...
    int wid = tid >> 6, lane = tid & 63;
    for (int b = wid; b < nb; b += 8) {
        int cnt = hist[b];
        int off = offs[b];
        int allow = gallow[b];
        unsigned* dst = segs + (size_t)b * SEG_CAP + gbase[b];
        for (int i = lane; i < allow; i += 64)
            dst[i] = pool[off + i];
        int excess = cnt - allow;
        if (excess > 0) {                 // never in practice
            int sb;
            if (lane == 0) sb = atomicAdd(spillcnt, excess);
            sb = __shfl(sb, 0);
            for (int i = lane; i < excess; i += 64) {
                int sp = sb + i;
                if (sp < SPILL_CAP) {
                    unsigned pv = pool[off + allow + i];
                    spill[sp] = make_int2((int)(pv >> BSHIFT),
                                          (b << BSHIFT) | (int)(pv & (BSIZE - 1)));
                }
            }
        }
    }
}

// ---------- gather + fused he-GEMM ----------
__global__ __launch_bounds__(512) void gather_he_kernel(
    const unsigned* __restrict__ segs, const int* __restrict__ gcnt,
    const int2* __restrict__ spill, const int* __restrict__ spillcnt,
    const float4* __restrict__ ea4,
    const float* __restrict__ We, const float* __restrict__ be,
    float* __restrict__ out, int N)
{
    __shared__ int counts[BSIZE];
    __shared__ int starts[BSIZE + 1];
    __shared__ int cursor[BSIZE];
    __shared__ int pool[POOL_SZ];       // ~14.6 KB edge ids
    __shared__ char sAgg[BSIZE * 64];   // agg tile [r][k] bf16 swizzled, 8 KB
    __shared__ char sWeT[128 * 64];     // We^T [j][k] bf16 swizzled, 8 KB

    int tid = threadIdx.x;
    int b = blockIdx.x;
    int node0 = b << BSHIFT;
    int lane = tid & 63, w = tid >> 6;
    int col = lane & 15, m = lane >> 4;

    if (tid < BSIZE) counts[tid] = 0;
    // stage We^T while counts settle
    for (int i = tid; i < 32 * 128; i += 512) {
        int k = i >> 7, j = i & 127;
        *(unsigned short*)(sWeT + j * 64 + ((k * 2) ^ ((j & 3) << 4))) = f2bf(We[i]);
    }
    __syncthreads();

    int segn = gcnt[b]; if (segn > SEG_CAP) segn = SEG_CAP;
    const unsigned* seg = segs + (size_t)b * SEG_CAP;
    int nsp = *spillcnt; if (nsp > SPILL_CAP) nsp = SPILL_CAP;

    // count
    for (int i = tid; i < segn; i += 512)
        atomicAdd(&counts[seg[i] & (BSIZE - 1)], 1);
    if (nsp)
        for (int i = tid; i < nsp; i += 512) {
            int2 p = spill[i];
            if ((p.y >> BSHIFT) == b) atomicAdd(&counts[p.y & (BSIZE - 1)], 1);
        }
    __syncthreads();

    // exclusive scan over 128 counters (wave 0, 2 per lane)
    if (tid < 64) {
        int c0 = counts[tid * 2], c1 = counts[tid * 2 + 1];
        int s = c0 + c1;
        int ws = s;
        #pragma unroll
        for (int d = 1; d < 64; d <<= 1) {
            int t = __shfl_up(ws, d);
            if (tid >= d) ws += t;
        }
        int ex = ws - s;
        starts[tid * 2] = ex;          cursor[tid * 2] = ex;
        starts[tid * 2 + 1] = ex + c0; cursor[tid * 2 + 1] = ex + c0;
        if (tid == 63) starts[BSIZE] = ws;
    }
    __syncthreads();

    // fill local CSR pool with edge ids
    for (int i = tid; i < segn; i += 512) {
        unsigned pe = seg[i];
        int pos = atomicAdd(&cursor[pe & (BSIZE - 1)], 1);
        if (pos < POOL_SZ) pool[pos] = (int)(pe >> BSHIFT);
    }
    if (nsp)
        for (int i = tid; i < nsp; i += 512) {
            int2 p = spill[i];
            if ((p.y >> BSHIFT) == b) {
                int pos = atomicAdd(&cursor[p.y & (BSIZE - 1)], 1);
                if (pos < POOL_SZ) pool[pos] = p.x;
            }
        }
    __syncthreads();

    // per-node register gather: 4 threads/node, quads q2 and q2+4,
    // 4-deep unroll => 8 independent loads in flight per thread.
    {
        int g = tid >> 2, q2 = tid & 3;
        int node = node0 + g;
        float4 aL0 = {0.f,0.f,0.f,0.f}, aL1 = {0.f,0.f,0.f,0.f};
        float4 aH0 = {0.f,0.f,0.f,0.f}, aH1 = {0.f,0.f,0.f,0.f};
        if (node < N) {
            int p0 = starts[g], p1 = starts[g + 1];
            if (p1 > POOL_SZ) p1 = POOL_SZ;
            int p = p0;
            for (; p + 4 <= p1; p += 4) {
                int e0 = pool[p], e1 = pool[p + 1], e2 = pool[p + 2], e3 = pool[p + 3];
                const float4* r0 = ea4 + (size_t)e0 * 8;
                const float4* r1 = ea4 + (size_t)e1 * 8;
                const float4* r2 = ea4 + (size_t)e2 * 8;
                const float4* r3 = ea4 + (size_t)e3 * 8;
                float4 l0 = r0[q2],     l1 = r1[q2],     l2 = r2[q2],     l3 = r3[q2];
                float4 h0 = r0[q2 + 4], h1 = r1[q2 + 4], h2 = r2[q2 + 4], h3 = r3[q2 + 4];
                aL0.x += l0.x; aL0.y += l0.y; aL0.z += l0.z; aL0.w += l0.w;
                aL1.x += l1.x; aL1.y += l1.y; aL1.z += l1.z; aL1.w += l1.w;
                aH0.x += h0.x; aH0.y += h0.y; aH0.z += h0.z; aH0.w += h0.w;
                aH1.x += h1.x; aH1.y += h1.y; aH1.z += h1.z; aH1.w += h1.w;
                aL0.x += l2.x; aL0.y += l2.y; aL0.z += l2.z; aL0.w += l2.w;
                aL1.x += l3.x; aL1.y += l3.y; aL1.z += l3.z; aL1.w += l3.w;
                aH0.x += h2.x; aH0.y += h2.y; aH0.z += h2.z; aH0.w += h2.w;
                aH1.x += h3.x; aH1.y += h3.y; aH1.z += h3.z; aH1.w += h3.w;
            }
            for (; p < p1; ++p) {
                const float4* r = ea4 + (size_t)pool[p] * 8;
                float4 l = r[q2], h = r[q2 + 4];
                aL0.x += l.x; aL0.y += l.y; aL0.z += l.z; aL0.w += l.w;
                aH0.x += h.x; aH0.y += h.y; aH0.z += h.z; aH0.w += h.w;
            }
            aL0.x += aL1.x; aL0.y += aL1.y; aL0.z += aL1.z; aL0.w += aL1.w;
            aH0.x += aH1.x; aH0.y += aH1.y; aH0.z += aH1.z; aH0.w += aH1.w;
        }
        // write agg rows into swizzled LDS (zeros for out-of-range nodes)
        uint2 lo, hi;
        lo.x = (unsigned)f2bf(aL0.x) | ((unsigned)f2bf(aL0.y) << 16);
        lo.y = (unsigned)f2bf(aL0.z) | ((unsigned)f2bf(aL0.w) << 16);
        hi.x = (unsigned)f2bf(aH0.x) | ((unsigned)f2bf(aH0.y) << 16);
        hi.y = (unsigned)f2bf(aH0.z) | ((unsigned)f2bf(aH0.w) << 16);
        int swz = (g & 7) << 4;
        *(uint2*)(sAgg + ((g * 64 + q2 * 8) ^ swz))            = lo;
        *(uint2*)(sAgg + ((g * 64 + (q2 + 4) * 8) ^ swz))      = hi;
    }
    __syncthreads();

    // fused he-GEMM: [128,32] @ We[32,128] + be -> out[:,128:256]
    {
        int lrow = (w << 4) + col;          // tile-local agg row this lane consumes
        bf16x8 aa = *(const bf16x8*)(sAgg + ((lrow * 64 + m * 16) ^ ((lrow & 7) << 4)));

        f32x4 acc[8];
        #pragma unroll
        for (int ct = 0; ct < 8; ++ct) {
            float bv = be[ct * 16 + col];
            acc[ct] = (f32x4){bv, bv, bv, bv};
        }
        #pragma unroll
        for (int ct = 0; ct < 8; ++ct) {
            bf16x8 bwe = *(const bf16x8*)(sWeT + (ct * 16 + col) * 64 + ((m * 16) ^ ((col & 3) << 4)));
            acc[ct] = __builtin_amdgcn_mfma_f32_16x16x32_bf16(aa, bwe, acc[ct], 0, 0, 0);
        }

        int srow = node0 + (w << 4) + m * 4;
        #pragma unroll
        for (int r = 0; r < 4; ++r) {
            if (srow + r < N) {
                float* orow = out + (size_t)(srow + r) * 256 + 128 + col;
                #pragma unroll
                for (int ct = 0; ct < 8; ++ct)
                    orow[ct * 16] = acc[ct][r];
            }
        }
    }
}

// ---------- fallback: atomic scatter + convert ----------
__global__ __launch_bounds__(256) void scatter_kernel(
    const float4* __restrict__ ea4, const int* __restrict__ src,
    float* __restrict__ agg, int nquads)
{
    int t = blockIdx.x * blockDim.x + threadIdx.x;
    if (t >= nquads) return;
    int e = t >> 3, q = t & 7;
    float4 v = ea4[t];
    int node = src[e];
    float* dst = agg + (size_t)node * 32 + q * 4;
    atomicAdd(dst + 0, v.x); atomicAdd(dst + 1, v.y);
    atomicAdd(dst + 2, v.z); atomicAdd(dst + 3, v.w);
}

__global__ __launch_bounds__(256) void cvt_kernel(
    const float* __restrict__ agg, unsigned short* __restrict__ aggbf, int n)
{
    int t = blockIdx.x * blockDim.x + threadIdx.x;
    if (t < n) aggbf[t] = f2bf(agg[t]);
}

// ---------- MFMA bf16 GEMM (x@Wx always; + agg@We when DO_HE) ----------
template <bool DO_HE>
__global__ __launch_bounds__(512, 4) void mfma_gemm(
    const float* __restrict__ x, const unsigned short* __restrict__ aggbf,
    const float* __restrict__ Wx, const float* __restrict__ bx,
    const float* __restrict__ We, const float* __restrict__ be,
    float* __restrict__ out, int N, int ntiles)
{
    __shared__ char sWxT[128 * 256];   // Wx^T [j][k] bf16, swizzled: 32 KB
    __shared__ char sWeT[128 * 64];    // We^T [j][k] bf16, swizzled:  8 KB
    __shared__ char sX[128 * 256];     // x-tile [r][k] bf16, swizzled: 32 KB
    __shared__ char sA[128 * 64];      // agg-tile [r][k] bf16, swizzled: 8 KB

    int tid = threadIdx.x;
    int lane = tid & 63, w = tid >> 6;
    int col = lane & 15, m = lane >> 4;

    // stage transposed weights (once per block)
    for (int i = tid; i < 128 * 128; i += 512) {
        int k = i >> 7, j = i & 127;
        *(unsigned short*)(sWxT + j * 256 + ((k * 2) ^ ((j & 7) << 4))) = f2bf(Wx[i]);
    }
    if (DO_HE)
        for (int i = tid; i < 32 * 128; i += 512) {
            int k = i >> 7, j = i & 127;
            *(unsigned short*)(sWeT + j * 64 + ((k * 2) ^ ((j & 3) << 4))) = f2bf(We[i]);
        }
    float bxv[8], bev[8];
    #pragma unroll
    for (int ct = 0; ct < 8; ++ct) {
        bxv[ct] = bx[ct * 16 + col];
        if (DO_HE) bev[ct] = be[ct * 16 + col];
    }

    int lrow = (w << 4) + col;          // tile-local A row this lane consumes
    int swzA = (lrow & 7) << 4;

    for (int t = blockIdx.x; t < ntiles; t += gridDim.x) {
        int rbase_t = t << 7;
        __syncthreads();                // protect prev-iter reads (and weights, 1st iter)

        // stage x-tile: coalesced float4 reads, swizzled bf16 LDS writes
        for (int i = tid; i < 128 * 32; i += 512) {
            int row = i >> 5, c4 = i & 31;
            int gr = rbase_t + row;
            float4 v = {0.f, 0.f, 0.f, 0.f};
            if (gr < N) v = *(const float4*)(x + (size_t)gr * 128 + c4 * 4);
            uint2 uu;
            uu.x = (unsigned)f2bf(v.x) | ((unsigned)f2bf(v.y) << 16);
            uu.y = (unsigned)f2bf(v.z) | ((unsigned)f2bf(v.w) << 16);
            *(uint2*)(sX + ((row * 256 + c4 * 8) ^ ((row & 7) << 4))) = uu;
        }
        if (DO_HE) {
            int row = tid >> 2, mm = tid & 3;
            int gr = rbase_t + row;
            bf16x8 av = {0, 0, 0, 0, 0, 0, 0, 0};
            if (gr < N) av = *(const bf16x8*)(aggbf + (size_t)gr * 32 + mm * 8);
            *(bf16x8*)(sA + ((row * 64 + mm * 16) ^ ((row & 7) << 4))) = av;
        }
        __syncthreads();

        // A fragments from LDS
        bf16x8 ax[4];
        #pragma unroll
        for (int kk = 0; kk < 4; ++kk)
            ax[kk] = *(const bf16x8*)(sX + lrow * 256 + ((kk * 64 + m * 16) ^ swzA));
        bf16x8 aa = {0,0,0,0,0,0,0,0};
        if (DO_HE) aa = *(const bf16x8*)(sA + ((lrow * 64 + m * 16) ^ swzA));

        int srow = rbase_t + (w << 4) + m * 4;

        #pragma unroll
        for (int half = 0; half < 2; ++half) {
            f32x4 acc[8];
            #pragma unroll
            for (int ct = 0; ct < 4; ++ct) {
                int c8 = half * 4 + ct;
                acc[ct] = (f32x4){bxv[c8], bxv[c8], bxv[c8], bxv[c8]};
                if (DO_HE) acc[4 + ct] = (f32x4){bev[c8], bev[c8], bev[c8], bev[c8]};
            }

            #pragma unroll
            for (int ct = 0; ct < 4; ++ct) {
                int c8 = half * 4 + ct;
                const char* brow = sWxT + (c8 * 16 + col) * 256;
                int swz = (col & 7) << 4;
                #pragma unroll
                for (int kk = 0; kk < 4; ++kk) {
                    bf16x8 bfrag = *(const bf16x8*)(brow + ((kk * 64 + m * 16) ^ swz));
                    acc[ct] = __builtin_amdgcn_mfma_f32_16x16x32_bf16(ax[kk], bfrag, acc[ct], 0, 0, 0);
                }
                if (DO_HE) {
                    bf16x8 bwe = *(const bf16x8*)(sWeT + (c8 * 16 + col) * 64 + ((m * 16) ^ ((col & 3) << 4)));
                    acc[4 + ct] = __builtin_amdgcn_mfma_f32_16x16x32_bf16(aa, bwe, acc[4 + ct], 0, 0, 0);
                }
            }

            #pragma unroll
            for (int r = 0; r < 4; ++r) {
                if (srow + r < N) {
                    float* orow = out + (size_t)(srow + r) * 256 + col + half * 64;
                    #pragma unroll
                    for (int ct = 0; ct < 4; ++ct) {
                        orow[ct * 16] = acc[ct][r];
                        if (DO_HE) orow[128 + ct * 16] = acc[4 + ct][r];
                    }
                }
            }
        }
    }
}

extern "C" void kernel_launch(void* const* d_in, const int* in_sizes, int n_in,
                              void* d_out, int out_size, void* d_ws, size_t ws_size,
                              hipStream_t stream) {
    const float* x          = (const float*)d_in[0];
    const int*   edge_index = (const int*)d_in[1];   // [2,E] flat; row 0 = src
    const float* edge_attr  = (const float*)d_in[2];
    const float* Wx         = (const float*)d_in[3];
    const float* bx         = (const float*)d_in[4];
    const float* We         = (const float*)d_in[5];
    const float* be         = (const float*)d_in[6];
    float* out = (float*)d_out;

    int N = in_sizes[0] / 128;
    int E = in_sizes[2] / 32;
    int nb = (N + BSIZE - 1) >> BSHIFT;
    int ntiles = (N + 127) >> 7;

    char* ws = (char*)d_ws;
    size_t aggbfBytes = ((size_t)N * 32 * 2 + 255) & ~255ull;
    size_t segsBytes  = ((size_t)nb * SEG_CAP * 4 + 255) & ~255ull;
    size_t gcntBytes  = ((size_t)(nb + 1) * 4 + 255) & ~255ull;
    size_t spillBytes = (size_t)SPILL_CAP * 8;
    size_t need = aggbfBytes + segsBytes + gcntBytes + spillBytes;

    unsigned short* aggbf = (unsigned short*)ws;

    int g = ntiles < 512 ? ntiles : 512;

    if (ws_size >= need && nb <= NBMAX) {
        unsigned* segs  = (unsigned*)(ws + aggbfBytes);
        int* gcnt       = (int*)(ws + aggbfBytes + segsBytes);
        int* spillcnt   = gcnt + nb;
        int2* spill     = (int2*)(ws + aggbfBytes + segsBytes + gcntBytes);

        hipMemsetAsync(gcnt, 0, (size_t)(nb + 1) * 4, stream);
        int nblkA = (E + CHUNK_A - 1) / CHUNK_A;
        binA_kernel<<<nblkA, 512, 0, stream>>>(edge_index, E, nb, segs, gcnt, spill, spillcnt);
        gather_he_kernel<<<nb, 512, 0, stream>>>(segs, gcnt, spill, spillcnt,
                                                 (const float4*)edge_attr, We, be, out, N);
        mfma_gemm<false><<<g, 512, 0, stream>>>(x, aggbf, Wx, bx, We, be, out, N, ntiles);
    } else {
        float* aggf = (float*)(ws + aggbfBytes);
        hipMemsetAsync(aggf, 0, (size_t)N * 32 * 4, stream);
        int nq = E * 8;
        scatter_kernel<<<(nq + 255) / 256, 256, 0, stream>>>(
            (const float4*)edge_attr, edge_index, aggf, nq);
        cvt_kernel<<<(N * 32 + 255) / 256, 256, 0, stream>>>(aggf, aggbf, N * 32);
        mfma_gemm<true><<<g, 512, 0, stream>>>(x, aggbf, Wx, bx, We, be, out, N, ntiles);
    }
}

// Round 10
// 147.217 us; speedup vs baseline: 3.8070x; 1.0215x over previous
//
#include <hip/hip_runtime.h>

// out[N,256] = concat( x[N,128] @ Wx[128,128] + bx,
//                      segsum(edge_attr by src)[N,32] @ We[32,128] + be )
//
// Pipeline:
//   binA:  bucket packed (edge_id<<7 | node&127) by src>>7 (128-node buckets)
//   fused: per bucket: local CSR in LDS -> register gather (4 thr/node,
//          8 loads in flight) -> hx MFMA (x@Wx, overlapped with sibling
//          waves' gather latency) -> barrier -> he MFMA (agg@We).
//          One kernel writes all 256 output columns for its 128 rows.

#define BSHIFT    7
#define BSIZE     128
#define NBMAX     1024
#define SEG_CAP   3584    // pairs per bucket (mean ~2046, sigma ~45, +34 sigma)
#define POOL_SZ   3648
#define CHUNK_A   8192
#define SPILL_CAP 65536

typedef short bf16x8 __attribute__((ext_vector_type(8)));
typedef float f32x4  __attribute__((ext_vector_type(4)));

__device__ __forceinline__ unsigned short f2bf(float f) {
    union { float f; unsigned u; } c; c.f = f;
    unsigned u = c.u;
    u += 0x7FFF + ((u >> 16) & 1);          // round-to-nearest-even
    return (unsigned short)(u >> 16);
}

// ---------- Pass A: bucket edges (packed 4B pairs) ----------
__global__ __launch_bounds__(512) void binA_kernel(
    const int* __restrict__ src, int E, int nb,
    unsigned* __restrict__ segs, int* __restrict__ gcnt,
    int2* __restrict__ spill, int* __restrict__ spillcnt)
{
    __shared__ unsigned pool[CHUNK_A];      // 32 KB
    __shared__ int hist[NBMAX];
    __shared__ int offs[NBMAX];
    __shared__ int lcur[NBMAX];
    __shared__ int gbase[NBMAX];
    __shared__ int gallow[NBMAX];
    __shared__ int wsum[8];

    int tid = threadIdx.x;
    int base = blockIdx.x * CHUNK_A;

    for (int i = tid; i < NBMAX; i += 512) hist[i] = 0;
    __syncthreads();

    // count pass; cache src values in registers for the place pass
    int srcv[CHUNK_A / 512];
    #pragma unroll
    for (int u = 0; u < CHUNK_A / 512; ++u) {
        int e = base + tid + u * 512;
        int s = (e < E) ? src[e] : -1;
        srcv[u] = s;
        if (s >= 0) atomicAdd(&hist[s >> BSHIFT], 1);
    }
    __syncthreads();

    // block exclusive scan: each thread owns buckets 2t, 2t+1
    {
        int t2 = tid * 2;
        int c0 = hist[t2], c1 = hist[t2 + 1];
        int s = c0 + c1;
        int lane = tid & 63, wid = tid >> 6;
        int ws = s;
        #pragma unroll
        for (int d = 1; d < 64; d <<= 1) {
            int t = __shfl_up(ws, d);
            if (lane >= d) ws += t;
        }
        if (lane == 63) wsum[wid] = ws;
        __syncthreads();
        int woff = 0;
        #pragma unroll
        for (int w = 0; w < 8; ++w) if (w < wid) woff += wsum[w];
        int ex = woff + ws - s;
        offs[t2] = ex;          lcur[t2] = ex;
        offs[t2 + 1] = ex + c0; lcur[t2 + 1] = ex + c0;
    }
    __syncthreads();

    // reserve global segment space
    {
        int t2 = tid * 2;
        #pragma unroll
        for (int u = 0; u < 2; ++u) {
            int b = t2 + u;
            if (b < nb) {
                int cnt = hist[b];
                int b0 = cnt ? atomicAdd(&gcnt[b], cnt) : 0;
                gbase[b] = b0;
                int allow = SEG_CAP - b0;
                if (allow < 0) allow = 0;
                if (allow > cnt) allow = cnt;
                gallow[b] = allow;
            }
        }
    }
    __syncthreads();

    // place packed pairs into LDS pool grouped by bucket (src from registers)
    #pragma unroll
    for (int u = 0; u < CHUNK_A / 512; ++u) {
        int s = srcv[u];
        if (s >= 0) {
            int e = base + tid + u * 512;
            int b = s >> BSHIFT;
            int p = atomicAdd(&lcur[b], 1);
            pool[p] = ((unsigned)e << BSHIFT) | (unsigned)(s & (BSIZE - 1));
        }
    }
    __syncthreads();

    // coalesced flush: wave w handles buckets w, w+8, ...
    int wid = tid >> 6, lane = tid & 63;
    for (int b = wid; b < nb; b += 8) {
        int cnt = hist[b];
        int off = offs[b];
        int allow = gallow[b];
        unsigned* dst = segs + (size_t)b * SEG_CAP + gbase[b];
        for (int i = lane; i < allow; i += 64)
            dst[i] = pool[off + i];
        int excess = cnt - allow;
        if (excess > 0) {                 // never in practice
            int sb;
            if (lane == 0) sb = atomicAdd(spillcnt, excess);
            sb = __shfl(sb, 0);
            for (int i = lane; i < excess; i += 64) {
                int sp = sb + i;
                if (sp < SPILL_CAP) {
                    unsigned pv = pool[off + allow + i];
                    spill[sp] = make_int2((int)(pv >> BSHIFT),
                                          (b << BSHIFT) | (int)(pv & (BSIZE - 1)));
                }
            }
        }
    }
}

// ---------- fused: CSR gather + hx MFMA + he MFMA ----------
__global__ __launch_bounds__(512, 4) void fused_kernel(
    const unsigned* __restrict__ segs, const int* __restrict__ gcnt,
    const int2* __restrict__ spill, const int* __restrict__ spillcnt,
    const float4* __restrict__ ea4, const float* __restrict__ x,
    const float* __restrict__ Wx, const float* __restrict__ bx,
    const float* __restrict__ We, const float* __restrict__ be,
    float* __restrict__ out, int N)
{
    __shared__ int counts[BSIZE];
    __shared__ int starts[BSIZE + 1];
    __shared__ int cursor[BSIZE];
    __shared__ int pool[POOL_SZ];       // ~14.3 KB edge ids
    __shared__ char sAgg[BSIZE * 64];   // agg tile [r][k] bf16 swizzled, 8 KB
    __shared__ char sWeT[128 * 64];     // We^T [j][k] bf16 swizzled, 8 KB
    __shared__ char sWxT[128 * 256];    // Wx^T [j][k] bf16 swizzled, 32 KB

    int tid = threadIdx.x;
    int b = blockIdx.x;
    int node0 = b << BSHIFT;
    int lane = tid & 63, w = tid >> 6;
    int col = lane & 15, m = lane >> 4;

    if (tid < BSIZE) counts[tid] = 0;
    // stage weights (reads are L2-hot after the first blocks)
    for (int i = tid; i < 128 * 128; i += 512) {
        int k = i >> 7, j = i & 127;
        *(unsigned short*)(sWxT + j * 256 + ((k * 2) ^ ((j & 7) << 4))) = f2bf(Wx[i]);
    }
    for (int i = tid; i < 32 * 128; i += 512) {
        int k = i >> 7, j = i & 127;
        *(unsigned short*)(sWeT + j * 64 + ((k * 2) ^ ((j & 3) << 4))) = f2bf(We[i]);
    }
    float bxv[8], bev[8];
    #pragma unroll
    for (int ct = 0; ct < 8; ++ct) {
        bxv[ct] = bx[ct * 16 + col];
        bev[ct] = be[ct * 16 + col];
    }
    __syncthreads();

    int segn = gcnt[b]; if (segn > SEG_CAP) segn = SEG_CAP;
    const unsigned* seg = segs + (size_t)b * SEG_CAP;
    int nsp = *spillcnt; if (nsp > SPILL_CAP) nsp = SPILL_CAP;

    // count
    for (int i = tid; i < segn; i += 512)
        atomicAdd(&counts[seg[i] & (BSIZE - 1)], 1);
    if (nsp)
        for (int i = tid; i < nsp; i += 512) {
            int2 p = spill[i];
            if ((p.y >> BSHIFT) == b) atomicAdd(&counts[p.y & (BSIZE - 1)], 1);
        }
    __syncthreads();

    // exclusive scan over 128 counters (wave 0, 2 per lane)
    if (tid < 64) {
        int c0 = counts[tid * 2], c1 = counts[tid * 2 + 1];
        int s = c0 + c1;
        int ws = s;
        #pragma unroll
        for (int d = 1; d < 64; d <<= 1) {
            int t = __shfl_up(ws, d);
            if (tid >= d) ws += t;
        }
        int ex = ws - s;
        starts[tid * 2] = ex;          cursor[tid * 2] = ex;
        starts[tid * 2 + 1] = ex + c0; cursor[tid * 2 + 1] = ex + c0;
        if (tid == 63) starts[BSIZE] = ws;
    }
    __syncthreads();

    // fill local CSR pool with edge ids
    for (int i = tid; i < segn; i += 512) {
        unsigned pe = seg[i];
        int pos = atomicAdd(&cursor[pe & (BSIZE - 1)], 1);
        if (pos < POOL_SZ) pool[pos] = (int)(pe >> BSHIFT);
    }
    if (nsp)
        for (int i = tid; i < nsp; i += 512) {
            int2 p = spill[i];
            if ((p.y >> BSHIFT) == b) {
                int pos = atomicAdd(&cursor[p.y & (BSIZE - 1)], 1);
                if (pos < POOL_SZ) pool[pos] = p.x;
            }
        }
    __syncthreads();

    // per-node register gather: 4 threads/node, quads q2 and q2+4,
    // 4-deep unroll => 8 independent loads in flight per thread.
    {
        int g = tid >> 2, q2 = tid & 3;
        int node = node0 + g;
        float4 aL0 = {0.f,0.f,0.f,0.f}, aL1 = {0.f,0.f,0.f,0.f};
        float4 aH0 = {0.f,0.f,0.f,0.f}, aH1 = {0.f,0.f,0.f,0.f};
        if (node < N) {
            int p0 = starts[g], p1 = starts[g + 1];
            if (p1 > POOL_SZ) p1 = POOL_SZ;
            int p = p0;
            for (; p + 4 <= p1; p += 4) {
                int e0 = pool[p], e1 = pool[p + 1], e2 = pool[p + 2], e3 = pool[p + 3];
                const float4* r0 = ea4 + (size_t)e0 * 8;
                const float4* r1 = ea4 + (size_t)e1 * 8;
                const float4* r2 = ea4 + (size_t)e2 * 8;
                const float4* r3 = ea4 + (size_t)e3 * 8;
                float4 l0 = r0[q2],     l1 = r1[q2],     l2 = r2[q2],     l3 = r3[q2];
                float4 h0 = r0[q2 + 4], h1 = r1[q2 + 4], h2 = r2[q2 + 4], h3 = r3[q2 + 4];
                aL0.x += l0.x; aL0.y += l0.y; aL0.z += l0.z; aL0.w += l0.w;
                aL1.x += l1.x; aL1.y += l1.y; aL1.z += l1.z; aL1.w += l1.w;
                aH0.x += h0.x; aH0.y += h0.y; aH0.z += h0.z; aH0.w += h0.w;
                aH1.x += h1.x; aH1.y += h1.y; aH1.z += h1.z; aH1.w += h1.w;
                aL0.x += l2.x; aL0.y += l2.y; aL0.z += l2.z; aL0.w += l2.w;
                aL1.x += l3.x; aL1.y += l3.y; aL1.z += l3.z; aL1.w += l3.w;
                aH0.x += h2.x; aH0.y += h2.y; aH0.z += h2.z; aH0.w += h2.w;
                aH1.x += h3.x; aH1.y += h3.y; aH1.z += h3.z; aH1.w += h3.w;
            }
            for (; p < p1; ++p) {
                const float4* r = ea4 + (size_t)pool[p] * 8;
                float4 l = r[q2], h = r[q2 + 4];
                aL0.x += l.x; aL0.y += l.y; aL0.z += l.z; aL0.w += l.w;
                aH0.x += h.x; aH0.y += h.y; aH0.z += h.z; aH0.w += h.w;
            }
            aL0.x += aL1.x; aL0.y += aL1.y; aL0.z += aL1.z; aL0.w += aL1.w;
            aH0.x += aH1.x; aH0.y += aH1.y; aH0.z += aH1.z; aH0.w += aH1.w;
        }
        // write agg rows into swizzled LDS (zeros for out-of-range nodes)
        uint2 lo, hi;
        lo.x = (unsigned)f2bf(aL0.x) | ((unsigned)f2bf(aL0.y) << 16);
        lo.y = (unsigned)f2bf(aL0.z) | ((unsigned)f2bf(aL0.w) << 16);
        hi.x = (unsigned)f2bf(aH0.x) | ((unsigned)f2bf(aH0.y) << 16);
        hi.y = (unsigned)f2bf(aH0.z) | ((unsigned)f2bf(aH0.w) << 16);
        int swz = (g & 7) << 4;
        *(uint2*)(sAgg + ((g * 64 + q2 * 8) ^ swz))       = lo;
        *(uint2*)(sAgg + ((g * 64 + (q2 + 4) * 8) ^ swz)) = hi;
    }

    // ---- hx GEMM (no barrier needed: weights staged, A-frags from global).
    // Runs while sibling waves are still in their gather loops.
    int lrow = (w << 4) + col;              // tile-local row this lane consumes
    int grow = node0 + lrow;
    bool rok = grow < N;
    int srow = node0 + (w << 4) + m * 4;

    {
        const float* xr = x + (size_t)grow * 128 + m * 8;
        bf16x8 ax[4];
        #pragma unroll
        for (int kk = 0; kk < 4; ++kk) {
            float4 p0 = {0.f,0.f,0.f,0.f}, p1 = {0.f,0.f,0.f,0.f};
            if (rok) {
                p0 = *(const float4*)(xr + kk * 32);
                p1 = *(const float4*)(xr + kk * 32 + 4);
            }
            bf16x8 a;
            a[0] = (short)f2bf(p0.x); a[1] = (short)f2bf(p0.y);
            a[2] = (short)f2bf(p0.z); a[3] = (short)f2bf(p0.w);
            a[4] = (short)f2bf(p1.x); a[5] = (short)f2bf(p1.y);
            a[6] = (short)f2bf(p1.z); a[7] = (short)f2bf(p1.w);
            ax[kk] = a;
        }

        #pragma unroll
        for (int half = 0; half < 2; ++half) {
            f32x4 acc[4];
            #pragma unroll
            for (int ct = 0; ct < 4; ++ct) {
                int c8 = half * 4 + ct;
                acc[ct] = (f32x4){bxv[c8], bxv[c8], bxv[c8], bxv[c8]};
            }
            #pragma unroll
            for (int ct = 0; ct < 4; ++ct) {
                int c8 = half * 4 + ct;
                const char* brow = sWxT + (c8 * 16 + col) * 256;
                int swz = (col & 7) << 4;
                #pragma unroll
                for (int kk = 0; kk < 4; ++kk) {
                    bf16x8 bfrag = *(const bf16x8*)(brow + ((kk * 64 + m * 16) ^ swz));
                    acc[ct] = __builtin_amdgcn_mfma_f32_16x16x32_bf16(ax[kk], bfrag, acc[ct], 0, 0, 0);
                }
            }
            #pragma unroll
            for (int r = 0; r < 4; ++r) {
                if (srow + r < N) {
                    float* orow = out + (size_t)(srow + r) * 256 + col + half * 64;
                    #pragma unroll
                    for (int ct = 0; ct < 4; ++ct)
                        orow[ct * 16] = acc[ct][r];
                }
            }
        }
    }

    __syncthreads();    // sAgg complete across all waves

    // ---- he GEMM: [128,32] @ We[32,128] + be -> out[:,128:256]
    {
        bf16x8 aa = *(const bf16x8*)(sAgg + ((lrow * 64 + m * 16) ^ ((lrow & 7) << 4)));

        f32x4 acc[8];
        #pragma unroll
        for (int ct = 0; ct < 8; ++ct)
            acc[ct] = (f32x4){bev[ct], bev[ct], bev[ct], bev[ct]};
        #pragma unroll
        for (int ct = 0; ct < 8; ++ct) {
            bf16x8 bwe = *(const bf16x8*)(sWeT + (ct * 16 + col) * 64 + ((m * 16) ^ ((col & 3) << 4)));
            acc[ct] = __builtin_amdgcn_mfma_f32_16x16x32_bf16(aa, bwe, acc[ct], 0, 0, 0);
        }

        #pragma unroll
        for (int r = 0; r < 4; ++r) {
            if (srow + r < N) {
                float* orow = out + (size_t)(srow + r) * 256 + 128 + col;
                #pragma unroll
                for (int ct = 0; ct < 8; ++ct)
                    orow[ct * 16] = acc[ct][r];
            }
        }
    }
}

// ---------- fallback: atomic scatter + convert + full GEMM ----------
__global__ __launch_bounds__(256) void scatter_kernel(
    const float4* __restrict__ ea4, const int* __restrict__ src,
    float* __restrict__ agg, int nquads)
{
    int t = blockIdx.x * blockDim.x + threadIdx.x;
    if (t >= nquads) return;
    int e = t >> 3, q = t & 7;
    float4 v = ea4[t];
    int node = src[e];
    float* dst = agg + (size_t)node * 32 + q * 4;
    atomicAdd(dst + 0, v.x); atomicAdd(dst + 1, v.y);
    atomicAdd(dst + 2, v.z); atomicAdd(dst + 3, v.w);
}

__global__ __launch_bounds__(256) void cvt_kernel(
    const float* __restrict__ agg, unsigned short* __restrict__ aggbf, int n)
{
    int t = blockIdx.x * blockDim.x + threadIdx.x;
    if (t < n) aggbf[t] = f2bf(agg[t]);
}

__global__ __launch_bounds__(512, 4) void mfma_gemm_full(
    const float* __restrict__ x, const unsigned short* __restrict__ aggbf,
    const float* __restrict__ Wx, const float* __restrict__ bx,
    const float* __restrict__ We, const float* __restrict__ be,
    float* __restrict__ out, int N, int ntiles)
{
    __shared__ char sWxT[128 * 256];
    __shared__ char sWeT[128 * 64];
    __shared__ char sX[128 * 256];
    __shared__ char sA[128 * 64];

    int tid = threadIdx.x;
    int lane = tid & 63, w = tid >> 6;
    int col = lane & 15, m = lane >> 4;

    for (int i = tid; i < 128 * 128; i += 512) {
        int k = i >> 7, j = i & 127;
        *(unsigned short*)(sWxT + j * 256 + ((k * 2) ^ ((j & 7) << 4))) = f2bf(Wx[i]);
    }
    for (int i = tid; i < 32 * 128; i += 512) {
        int k = i >> 7, j = i & 127;
        *(unsigned short*)(sWeT + j * 64 + ((k * 2) ^ ((j & 3) << 4))) = f2bf(We[i]);
    }
    float bxv[8], bev[8];
    #pragma unroll
    for (int ct = 0; ct < 8; ++ct) {
        bxv[ct] = bx[ct * 16 + col];
        bev[ct] = be[ct * 16 + col];
    }

    int lrow = (w << 4) + col;
    int swzA = (lrow & 7) << 4;

    for (int t = blockIdx.x; t < ntiles; t += gridDim.x) {
        int rbase_t = t << 7;
        __syncthreads();

        for (int i = tid; i < 128 * 32; i += 512) {
            int row = i >> 5, c4 = i & 31;
            int gr = rbase_t + row;
            float4 v = {0.f, 0.f, 0.f, 0.f};
            if (gr < N) v = *(const float4*)(x + (size_t)gr * 128 + c4 * 4);
            uint2 uu;
            uu.x = (unsigned)f2bf(v.x) | ((unsigned)f2bf(v.y) << 16);
            uu.y = (unsigned)f2bf(v.z) | ((unsigned)f2bf(v.w) << 16);
            *(uint2*)(sX + ((row * 256 + c4 * 8) ^ ((row & 7) << 4))) = uu;
        }
        {
            int row = tid >> 2, mm = tid & 3;
            int gr = rbase_t + row;
            bf16x8 av = {0, 0, 0, 0, 0, 0, 0, 0};
            if (gr < N) av = *(const bf16x8*)(aggbf + (size_t)gr * 32 + mm * 8);
            *(bf16x8*)(sA + ((row * 64 + mm * 16) ^ ((row & 7) << 4))) = av;
        }
        __syncthreads();

        bf16x8 ax[4];
        #pragma unroll
        for (int kk = 0; kk < 4; ++kk)
            ax[kk] = *(const bf16x8*)(sX + lrow * 256 + ((kk * 64 + m * 16) ^ swzA));
        bf16x8 aa = *(const bf16x8*)(sA + ((lrow * 64 + m * 16) ^ swzA));

        int srow = rbase_t + (w << 4) + m * 4;

        #pragma unroll
        for (int half = 0; half < 2; ++half) {
            f32x4 acc[8];
            #pragma unroll
            for (int ct = 0; ct < 4; ++ct) {
                int c8 = half * 4 + ct;
                acc[ct]     = (f32x4){bxv[c8], bxv[c8], bxv[c8], bxv[c8]};
                acc[4 + ct] = (f32x4){bev[c8], bev[c8], bev[c8], bev[c8]};
            }
            #pragma unroll
            for (int ct = 0; ct < 4; ++ct) {
                int c8 = half * 4 + ct;
                const char* brow = sWxT + (c8 * 16 + col) * 256;
                int swz = (col & 7) << 4;
                #pragma unroll
                for (int kk = 0; kk < 4; ++kk) {
                    bf16x8 bfrag = *(const bf16x8*)(brow + ((kk * 64 + m * 16) ^ swz));
                    acc[ct] = __builtin_amdgcn_mfma_f32_16x16x32_bf16(ax[kk], bfrag, acc[ct], 0, 0, 0);
                }
                bf16x8 bwe = *(const bf16x8*)(sWeT + (c8 * 16 + col) * 64 + ((m * 16) ^ ((col & 3) << 4)));
                acc[4 + ct] = __builtin_amdgcn_mfma_f32_16x16x32_bf16(aa, bwe, acc[4 + ct], 0, 0, 0);
            }
            #pragma unroll
            for (int r = 0; r < 4; ++r) {
                if (srow + r < N) {
                    float* orow = out + (size_t)(srow + r) * 256 + col + half * 64;
                    #pragma unroll
                    for (int ct = 0; ct < 4; ++ct) {
                        orow[ct * 16]       = acc[ct][r];
                        orow[128 + ct * 16] = acc[4 + ct][r];
                    }
                }
            }
        }
    }
}

extern "C" void kernel_launch(void* const* d_in, const int* in_sizes, int n_in,
                              void* d_out, int out_size, void* d_ws, size_t ws_size,
                              hipStream_t stream) {
    const float* x          = (const float*)d_in[0];
    const int*   edge_index = (const int*)d_in[1];   // [2,E] flat; row 0 = src
    const float* edge_attr  = (const float*)d_in[2];
    const float* Wx         = (const float*)d_in[3];
    const float* bx         = (const float*)d_in[4];
    const float* We         = (const float*)d_in[5];
    const float* be         = (const float*)d_in[6];
    float* out = (float*)d_out;

    int N = in_sizes[0] / 128;
    int E = in_sizes[2] / 32;
    int nb = (N + BSIZE - 1) >> BSHIFT;
    int ntiles = (N + 127) >> 7;

    char* ws = (char*)d_ws;
    size_t aggbfBytes = ((size_t)N * 32 * 2 + 255) & ~255ull;
    size_t segsBytes  = ((size_t)nb * SEG_CAP * 4 + 255) & ~255ull;
    size_t gcntBytes  = ((size_t)(nb + 1) * 4 + 255) & ~255ull;
    size_t spillBytes = (size_t)SPILL_CAP * 8;
    size_t need = aggbfBytes + segsBytes + gcntBytes + spillBytes;

    unsigned short* aggbf = (unsigned short*)ws;

    if (ws_size >= need && nb <= NBMAX) {
        unsigned* segs  = (unsigned*)(ws + aggbfBytes);
        int* gcnt       = (int*)(ws + aggbfBytes + segsBytes);
        int* spillcnt   = gcnt + nb;
        int2* spill     = (int2*)(ws + aggbfBytes + segsBytes + gcntBytes);

        hipMemsetAsync(gcnt, 0, (size_t)(nb + 1) * 4, stream);
        int nblkA = (E + CHUNK_A - 1) / CHUNK_A;
        binA_kernel<<<nblkA, 512, 0, stream>>>(edge_index, E, nb, segs, gcnt, spill, spillcnt);
        fused_kernel<<<nb, 512, 0, stream>>>(segs, gcnt, spill, spillcnt,
                                             (const float4*)edge_attr, x,
                                             Wx, bx, We, be, out, N);
    } else {
        float* aggf = (float*)(ws + aggbfBytes);
        hipMemsetAsync(aggf, 0, (size_t)N * 32 * 4, stream);
        int nq = E * 8;
        scatter_kernel<<<(nq + 255) / 256, 256, 0, stream>>>(
            (const float4*)edge_attr, edge_index, aggf, nq);
        cvt_kernel<<<(N * 32 + 255) / 256, 256, 0, stream>>>(aggf, aggbf, N * 32);
        int g = ntiles < 512 ? ntiles : 512;
        mfma_gemm_full<<<g, 512, 0, stream>>>(x, aggbf, Wx, bx, We, be, out, N, ntiles);
    }
}